// Round 4
// baseline (1475.448 us; speedup 1.0000x reference)
//
#include <hip/hip_runtime.h>
#include <hip/hip_bf16.h>
#include <math.h>

#define NB 128
#define NT 20
#define NS 19
#define NR 49
#define NV 10000
#define NE 512
#define NH 512
#define NFD 512
#define NA 256
#define NG 2048
#define NKC 1536
#define NBLK 128

typedef __bf16 bf16_t;
typedef bf16_t bf16x8 __attribute__((ext_vector_type(8)));
typedef float f32x4 __attribute__((ext_vector_type(4)));

__device__ __forceinline__ float sigm(float x) { return 1.f / (1.f + expf(-x)); }

// monotone-counter grid barrier (all NBLK blocks co-resident via coop launch)
__device__ __forceinline__ void grid_sync(unsigned* cnt, unsigned target)
{
    __syncthreads();
    if (threadIdx.x == 0) {
        __threadfence();                       // release: my writes visible
        atomicAdd(cnt, 1u);
        while (__hip_atomic_load(cnt, __ATOMIC_RELAXED, __HIP_MEMORY_SCOPE_AGENT) < target)
            __builtin_amdgcn_s_sleep(1);
        __threadfence();                       // acquire: see others' writes
    }
    __syncthreads();
}

// ------------------------------------------------------------------
// setup: Wcatb reordered (row n' = 4h+gate), bias reordered, bf16 copies
// of fc_W / W_f / W_h / features, hx=cx=0
// ------------------------------------------------------------------
__global__ __launch_bounds__(256) void k_setup(
    const float* __restrict__ W_ih, const float* __restrict__ W_hh,
    const float* __restrict__ b_ih, const float* __restrict__ b_hh,
    const float* __restrict__ W_h, const float* __restrict__ fc_W,
    const float* __restrict__ W_f, const float* __restrict__ features,
    bf16_t* __restrict__ Wcatb, bf16_t* __restrict__ fcWb,
    bf16_t* __restrict__ Wfb, bf16_t* __restrict__ featb,
    bf16_t* __restrict__ W_hb, float* __restrict__ bias,
    float* __restrict__ hx, float* __restrict__ cx)
{
    int idx = blockIdx.x * 256 + threadIdx.x;
    if (idx < NV * NH) fcWb[idx] = (bf16_t)fc_W[idx];
    if (idx < NG * NKC) {
        int n = idx / NKC, k = idx % NKC;      // n' = 4h + g
        int h = n >> 2, g = n & 3;
        int orig = g * NH + h;
        Wcatb[idx] = (bf16_t)((k < NE + NFD) ? W_ih[orig * (NE + NFD) + k]
                                             : W_hh[orig * NH + (k - NE - NFD)]);
    }
    if (idx < NB * NR * NFD) featb[idx] = (bf16_t)features[idx];
    if (idx < NA * NFD) Wfb[idx] = (bf16_t)W_f[idx];
    if (idx < NA * NH) W_hb[idx] = (bf16_t)W_h[idx];
    if (idx < NG) {
        int h = idx >> 2, g = idx & 3;
        int orig = g * NH + h;
        bias[idx] = b_ih[orig] + b_hh[orig];
    }
    if (idx < NB * NH) { hx[idx] = 0.f; cx[idx] = 0.f; }
}

// ------------------------------------------------------------------
// generic bf16 MFMA GEMM-NT (f_proj): C = A[M,K] @ B[N,K]^T + bias
// ------------------------------------------------------------------
__global__ __launch_bounds__(256) void gemm_bf16_nt(
    const bf16_t* __restrict__ Am, const bf16_t* __restrict__ Bm,
    const float* __restrict__ bias, float* __restrict__ Cm,
    int M, int N, int K, int ldc)
{
    __shared__ uint4 AsU[512];
    __shared__ uint4 BsU[512];
    int tid = threadIdx.x;
    int m0 = blockIdx.x * 64, n0 = blockIdx.y * 64;
    int nk = K >> 6;

    int rowS = tid >> 3, slotS = tid & 7;
    int wr0 = rowS * 8 + (slotS ^ (rowS & 7));
    int rowS2 = rowS + 32;
    int wr1 = rowS2 * 8 + (slotS ^ (rowS2 & 7));

    const uint4* pA = (const uint4*)(Am + (size_t)(m0 + rowS) * K) + slotS;
    size_t aStep = (size_t)4 * K;
    int nrow0 = n0 + rowS, nrow1 = n0 + rowS2;
    bool bv0 = nrow0 < N, bv1 = nrow1 < N;
    const uint4* pB0 = (const uint4*)(Bm + (size_t)nrow0 * K) + slotS;
    const uint4* pB1 = (const uint4*)(Bm + (size_t)nrow1 * K) + slotS;
    uint4 zz = make_uint4(0, 0, 0, 0);

    int w = tid >> 6, lane = tid & 63;
    int wm = w >> 1, wn = w & 1;
    int lr = lane & 15, lg = lane >> 4;
    int ra[2][2], rb[2][2];
    #pragma unroll
    for (int i = 0; i < 2; ++i)
        #pragma unroll
        for (int kk = 0; kk < 2; ++kk) {
            int rA = wm * 32 + i * 16 + lr;
            int rB = wn * 32 + i * 16 + lr;
            int s = kk * 4 + lg;
            ra[i][kk] = rA * 8 + (s ^ (rA & 7));
            rb[i][kk] = rB * 8 + (s ^ (rB & 7));
        }

    f32x4 acc00 = {}, acc01 = {}, acc10 = {}, acc11 = {};
    uint4 a0 = pA[0], a1 = pA[aStep];
    uint4 b0 = bv0 ? pB0[0] : zz;
    uint4 b1 = bv1 ? pB1[0] : zz;
    pA += 8; pB0 += 8; pB1 += 8;

    for (int kt = 0; kt < nk; ++kt) {
        __syncthreads();
        AsU[wr0] = a0; AsU[wr1] = a1;
        BsU[wr0] = b0; BsU[wr1] = b1;
        if (kt + 1 < nk) {
            a0 = pA[0]; a1 = pA[aStep];
            b0 = bv0 ? pB0[0] : zz;
            b1 = bv1 ? pB1[0] : zz;
            pA += 8; pB0 += 8; pB1 += 8;
        }
        __syncthreads();
        const bf16x8* Af = (const bf16x8*)AsU;
        const bf16x8* Bf = (const bf16x8*)BsU;
        #pragma unroll
        for (int kk = 0; kk < 2; ++kk) {
            bf16x8 fa0 = Af[ra[0][kk]], fa1 = Af[ra[1][kk]];
            bf16x8 fb0 = Bf[rb[0][kk]], fb1 = Bf[rb[1][kk]];
            acc00 = __builtin_amdgcn_mfma_f32_16x16x32_bf16(fa0, fb0, acc00, 0, 0, 0);
            acc01 = __builtin_amdgcn_mfma_f32_16x16x32_bf16(fa0, fb1, acc01, 0, 0, 0);
            acc10 = __builtin_amdgcn_mfma_f32_16x16x32_bf16(fa1, fb0, acc10, 0, 0, 0);
            acc11 = __builtin_amdgcn_mfma_f32_16x16x32_bf16(fa1, fb1, acc11, 0, 0, 0);
        }
    }

    f32x4 av[2][2] = {{acc00, acc01}, {acc10, acc11}};
    #pragma unroll
    for (int i = 0; i < 2; ++i) {
        int mbase = m0 + wm * 32 + i * 16 + lg * 4;
        #pragma unroll
        for (int j = 0; j < 2; ++j) {
            int n = n0 + wn * 32 + j * 16 + lr;
            if (n < N) {
                float bz = bias ? bias[n] : 0.f;
                #pragma unroll
                for (int r = 0; r < 4; ++r)
                    Cm[(size_t)(mbase + r) * ldc + n] = av[i][j][r] + bz;
            }
        }
    }
}

// ------------------------------------------------------------------
// persistent cooperative loop kernel: 128 blocks x 512 threads.
// per iteration t: [attention, block b=bid] -> gridsync ->
//                  [gates GEMM 32x64 tile + LSTM epilogue] -> gridsync
// ------------------------------------------------------------------
__global__ __launch_bounds__(512) void k_loop(
    const bf16_t* __restrict__ Wcatb, const bf16_t* __restrict__ W_hb,
    const float* __restrict__ b_h, const float* __restrict__ fproj,
    const float* __restrict__ v_w, const bf16_t* __restrict__ featb,
    const float* __restrict__ emb, const int* __restrict__ captions,
    const float* __restrict__ bias,
    bf16_t* __restrict__ lin, float* __restrict__ hx, float* __restrict__ cx,
    bf16_t* __restrict__ hxAll, unsigned* __restrict__ bar)
{
    __shared__ union {
        struct { float hxs[NH]; float part[2][NA]; float salpha[64]; } att;
        struct { uint4 AsU[256]; uint4 BsU[512]; } g;
        float Ct[32 * 65];
    } sm;

    int tid = threadIdx.x;
    int bid = blockIdx.x;
    int lane = tid & 63;
    unsigned bcount = 0;

    // ---- gates-phase constants ----
    int m0 = (bid & 3) * 32;          // batch-tile base
    int n0 = (bid >> 2) * 64;         // gate-col base
    int sRow = tid >> 3, sSlot = tid & 7;          // staging (row, 16B slot)
    int wrS = sRow * 8 + (sSlot ^ (sRow & 7));
    const uint4* pB_base = (const uint4*)(Wcatb + (size_t)(n0 + sRow) * NKC) + sSlot;
    const uint4* pA_base = (tid < 256)
        ? (const uint4*)(lin + (size_t)(m0 + sRow) * NKC) + sSlot : (const uint4*)0;

    int w = tid >> 6;
    int wm = w & 1, wn = w >> 1;      // wave tile 16x16 at (wm*16, wn*16)
    int lr = lane & 15, lg = lane >> 4;
    int raIdx[2], rbIdx[2];
    #pragma unroll
    for (int kk = 0; kk < 2; ++kk) {
        int rA = wm * 16 + lr;
        int rB = wn * 16 + lr;
        int s = kk * 4 + lg;
        raIdx[kk] = rA * 8 + (s ^ (rA & 7));
        rbIdx[kk] = rB * 8 + (s ^ (rB & 7));
    }

    for (int t = 0; t < NS; ++t) {
        // ================= attention (block b = bid) =================
        int b = bid;
        sm.att.hxs[tid] = hx[b * NH + tid];
        __syncthreads();
        {   // h-partials: thread (q = tid>>8, a = tid&255), half-K dot
            int a = tid & 255, q = tid >> 8;
            const bf16x8* wrow = (const bf16x8*)(W_hb + (size_t)a * NH + q * 256);
            const float* hq = sm.att.hxs + q * 256;
            float p = 0.f;
            #pragma unroll
            for (int c2 = 0; c2 < 32; ++c2) {
                bf16x8 wv = wrow[c2];
                int k = c2 * 8;
                p += hq[k+0]*(float)wv[0] + hq[k+1]*(float)wv[1]
                   + hq[k+2]*(float)wv[2] + hq[k+3]*(float)wv[3]
                   + hq[k+4]*(float)wv[4] + hq[k+5]*(float)wv[5]
                   + hq[k+6]*(float)wv[6] + hq[k+7]*(float)wv[7];
            }
            sm.att.part[q][a] = p;
        }
        __syncthreads();
        {   // scores: 8 waves strided over r (reads part directly)
            for (int r = w; r < NR; r += 8) {
                const float* fp = fproj + ((size_t)b * NR + r) * NA;
                float s = 0.f;
                #pragma unroll
                for (int j = 0; j < 4; ++j) {
                    int aa = lane + 64 * j;
                    float hv = sm.att.part[0][aa] + sm.att.part[1][aa] + b_h[aa];
                    s += tanhf(hv + fp[aa]) * v_w[aa];
                }
                #pragma unroll
                for (int off = 32; off; off >>= 1) s += __shfl_xor(s, off);
                if (lane == 0) sm.att.salpha[r] = s;
            }
        }
        __syncthreads();
        if (tid < 64) {   // softmax over R=49 in wave 0
            float v = (tid < NR) ? sm.att.salpha[tid] : -INFINITY;
            float m = v;
            #pragma unroll
            for (int off = 32; off; off >>= 1) m = fmaxf(m, __shfl_xor(m, off));
            float e = (tid < NR) ? expf(v - m) : 0.f;
            float ssum = e;
            #pragma unroll
            for (int off = 32; off; off >>= 1) ssum += __shfl_xor(ssum, off);
            if (tid < NR) sm.att.salpha[tid] = e / ssum;
        }
        __syncthreads();
        {   // context + concat lstm input row (bf16)
            bf16_t* lrow = lin + (size_t)b * NKC;
            int cap = captions[b * NT + t];
            lrow[tid] = (bf16_t)emb[(size_t)cap * NE + tid];
            lrow[NE + NFD + tid] = (bf16_t)sm.att.hxs[tid];
            float c = 0.f;
            #pragma unroll 7
            for (int r = 0; r < NR; ++r)
                c += sm.att.salpha[r] * (float)featb[((size_t)b * NR + r) * NFD + tid];
            lrow[NE + tid] = (bf16_t)c;
        }
        grid_sync(bar, (++bcount) * NBLK);

        // ============ gates GEMM (32x64 tile) + LSTM epilogue ============
        {
            const uint4* pA = pA_base;
            const uint4* pB = pB_base;
            f32x4 acc = {};
            uint4 aR = {}, bR;
            bR = pB[0]; pB += 8;
            if (tid < 256) { aR = pA[0]; pA += 8; }
            #pragma unroll 1
            for (int kt = 0; kt < NKC / 64; ++kt) {
                __syncthreads();
                sm.g.BsU[wrS] = bR;
                if (tid < 256) sm.g.AsU[wrS] = aR;
                if (kt + 1 < NKC / 64) {
                    bR = pB[0]; pB += 8;
                    if (tid < 256) { aR = pA[0]; pA += 8; }
                }
                __syncthreads();
                const bf16x8* Af = (const bf16x8*)sm.g.AsU;
                const bf16x8* Bf = (const bf16x8*)sm.g.BsU;
                #pragma unroll
                for (int kk = 0; kk < 2; ++kk) {
                    bf16x8 fa = Af[raIdx[kk]];
                    bf16x8 fb = Bf[rbIdx[kk]];
                    acc = __builtin_amdgcn_mfma_f32_16x16x32_bf16(fa, fb, acc, 0, 0, 0);
                }
            }
            __syncthreads();
            {   // stage gate tile (fp32) into LDS
                int crow = wm * 16 + lg * 4;
                int ccol = wn * 16 + lr;
                #pragma unroll
                for (int r = 0; r < 4; ++r)
                    sm.Ct[(crow + r) * 65 + ccol] = acc[r];
            }
            __syncthreads();
            {   // LSTM pointwise: thread -> (m = tid>>4, hloc = tid&15)
                int hloc = tid & 15, m = tid >> 4;
                int bb = m0 + m;
                int h = (n0 >> 2) + hloc;
                const float* crow = sm.Ct + m * 65 + hloc * 4;
                const float* brow = bias + n0 + hloc * 4;
                float gi = crow[0] + brow[0];
                float gf = crow[1] + brow[1];
                float gg = crow[2] + brow[2];
                float go = crow[3] + brow[3];
                size_t idx = (size_t)bb * NH + h;
                float c = sigm(gf) * cx[idx] + sigm(gi) * tanhf(gg);
                float hn = sigm(go) * tanhf(c);
                cx[idx] = c;
                hx[idx] = hn;
                hxAll[((size_t)t * NB + bb) * NH + h] = (bf16_t)hn;
            }
        }
        grid_sync(bar, (++bcount) * NBLK);
    }
}

// ------------------------------------------------------------------
// batched logits GEMM with XCD-bijective block swizzle (m204):
// A = hxAll [NS*NB, NH] bf16, B = fcWb [NV, NH]; 1D grid 38*157.
// ------------------------------------------------------------------
__global__ __launch_bounds__(256) void k_logits(
    const bf16_t* __restrict__ hxAll, const bf16_t* __restrict__ fcWb,
    const float* __restrict__ fc_b, float* __restrict__ out)
{
    const int MT = 38, NWG = 38 * 157;
    int bid0 = blockIdx.x;
    int q = NWG >> 3, r = NWG & 7;
    int xcd = bid0 & 7, loc = bid0 >> 3;
    int swz = (xcd < r ? xcd * (q + 1) : r * (q + 1) + (xcd - r) * q) + loc;
    int m0 = (swz % MT) * 64;
    int n0 = (swz / MT) * 64;

    __shared__ uint4 AsU[512];
    __shared__ uint4 BsU[512];
    int tid = threadIdx.x;

    int rowS = tid >> 3, slotS = tid & 7;
    int wr0 = rowS * 8 + (slotS ^ (rowS & 7));
    int rowS2 = rowS + 32;
    int wr1 = rowS2 * 8 + (slotS ^ (rowS2 & 7));

    const uint4* pA = (const uint4*)(hxAll + (size_t)(m0 + rowS) * NH) + slotS;
    size_t aStep = (size_t)4 * NH;
    int nrow0 = n0 + rowS, nrow1 = n0 + rowS2;
    bool bv0 = nrow0 < NV, bv1 = nrow1 < NV;
    const uint4* pB0 = (const uint4*)(fcWb + (size_t)nrow0 * NH) + slotS;
    const uint4* pB1 = (const uint4*)(fcWb + (size_t)nrow1 * NH) + slotS;
    uint4 zz = make_uint4(0, 0, 0, 0);

    int w = tid >> 6, lane = tid & 63;
    int wm = w >> 1, wn = w & 1;
    int lr = lane & 15, lg = lane >> 4;
    int ra[2][2], rb[2][2];
    #pragma unroll
    for (int i = 0; i < 2; ++i)
        #pragma unroll
        for (int kk = 0; kk < 2; ++kk) {
            int rA = wm * 32 + i * 16 + lr;
            int rB = wn * 32 + i * 16 + lr;
            int s = kk * 4 + lg;
            ra[i][kk] = rA * 8 + (s ^ (rA & 7));
            rb[i][kk] = rB * 8 + (s ^ (rB & 7));
        }

    f32x4 acc00 = {}, acc01 = {}, acc10 = {}, acc11 = {};
    uint4 a0 = pA[0], a1 = pA[aStep];
    uint4 b0 = bv0 ? pB0[0] : zz;
    uint4 b1 = bv1 ? pB1[0] : zz;
    pA += 8; pB0 += 8; pB1 += 8;

    #pragma unroll 1
    for (int kt = 0; kt < NH / 64; ++kt) {
        __syncthreads();
        AsU[wr0] = a0; AsU[wr1] = a1;
        BsU[wr0] = b0; BsU[wr1] = b1;
        if (kt + 1 < NH / 64) {
            a0 = pA[0]; a1 = pA[aStep];
            b0 = bv0 ? pB0[0] : zz;
            b1 = bv1 ? pB1[0] : zz;
            pA += 8; pB0 += 8; pB1 += 8;
        }
        __syncthreads();
        const bf16x8* Af = (const bf16x8*)AsU;
        const bf16x8* Bf = (const bf16x8*)BsU;
        #pragma unroll
        for (int kk = 0; kk < 2; ++kk) {
            bf16x8 fa0 = Af[ra[0][kk]], fa1 = Af[ra[1][kk]];
            bf16x8 fb0 = Bf[rb[0][kk]], fb1 = Bf[rb[1][kk]];
            acc00 = __builtin_amdgcn_mfma_f32_16x16x32_bf16(fa0, fb0, acc00, 0, 0, 0);
            acc01 = __builtin_amdgcn_mfma_f32_16x16x32_bf16(fa0, fb1, acc01, 0, 0, 0);
            acc10 = __builtin_amdgcn_mfma_f32_16x16x32_bf16(fa1, fb0, acc10, 0, 0, 0);
            acc11 = __builtin_amdgcn_mfma_f32_16x16x32_bf16(fa1, fb1, acc11, 0, 0, 0);
        }
    }

    f32x4 av[2][2] = {{acc00, acc01}, {acc10, acc11}};
    #pragma unroll
    for (int i = 0; i < 2; ++i) {
        int mbase = m0 + wm * 32 + i * 16 + lg * 4;
        #pragma unroll
        for (int j = 0; j < 2; ++j) {
            int n = n0 + wn * 32 + j * 16 + lr;
            if (n < NV) {
                float bz = fc_b[n];
                #pragma unroll
                for (int r = 0; r < 4; ++r) {
                    int m = mbase + r;
                    int bb = m & 127, tt = m >> 7;
                    out[((size_t)bb * NS + tt) * NV + n] = av[i][j][r] + bz;
                }
            }
        }
    }
}

// ------------------------------------------------------------------
extern "C" void kernel_launch(void* const* d_in, const int* in_sizes, int n_in,
                              void* d_out, int out_size, void* d_ws, size_t ws_size,
                              hipStream_t stream)
{
    const float* features = (const float*)d_in[0];
    const int*   captions = (const int*)d_in[1];
    const float* emb      = (const float*)d_in[2];
    const float* W_h      = (const float*)d_in[3];
    const float* b_h      = (const float*)d_in[4];
    const float* W_f      = (const float*)d_in[5];
    const float* b_f      = (const float*)d_in[6];
    const float* v_w      = (const float*)d_in[7];
    // d_in[8] = v_b : cancels in softmax
    const float* W_ih     = (const float*)d_in[9];
    const float* W_hh     = (const float*)d_in[10];
    const float* b_ih     = (const float*)d_in[11];
    const float* b_hh     = (const float*)d_in[12];
    const float* fc_W     = (const float*)d_in[13];
    const float* fc_b     = (const float*)d_in[14];
    float* out = (float*)d_out;

    char* base = (char*)d_ws;
    unsigned* bar = (unsigned*)base; base += 256;
    bf16_t* Wcatb = (bf16_t*)base;  base += (size_t)NG * NKC * 2;
    bf16_t* fcWb  = (bf16_t*)base;  base += (size_t)NV * NH * 2;
    bf16_t* Wfb   = (bf16_t*)base;  base += (size_t)NA * NFD * 2;
    bf16_t* featb = (bf16_t*)base;  base += (size_t)NB * NR * NFD * 2;
    bf16_t* lin   = (bf16_t*)base;  base += (size_t)NB * NKC * 2;
    bf16_t* W_hb  = (bf16_t*)base;  base += (size_t)NA * NH * 2;
    bf16_t* hxAll = (bf16_t*)base;  base += (size_t)NS * NB * NH * 2;
    float* bias   = (float*)base;   base += (size_t)NG * 4;
    float* fproj  = (float*)base;   base += (size_t)NB * NR * NA * 4;
    float* hx     = (float*)base;   base += (size_t)NB * NH * 4;
    float* cx     = (float*)base;   base += (size_t)NB * NH * 4;
    // total ~33.3 MB

    hipMemsetAsync(bar, 0, sizeof(unsigned), stream);

    k_setup<<<dim3((NV * NH + 255) / 256), 256, 0, stream>>>(
        W_ih, W_hh, b_ih, b_hh, W_h, fc_W, W_f, features,
        Wcatb, fcWb, Wfb, featb, W_hb, bias, hx, cx);

    // f_proj = features @ W_f^T + b_f : (6272 x 256), K=512
    gemm_bf16_nt<<<dim3(98, 4), 256, 0, stream>>>(
        featb, Wfb, b_f, fproj, NB * NR, NA, NFD, NA);

    // persistent 19-step recurrence (cooperative: all 128 blocks resident)
    void* kargs[] = {
        (void*)&Wcatb, (void*)&W_hb, (void*)&b_h, (void*)&fproj,
        (void*)&v_w, (void*)&featb, (void*)&emb, (void*)&captions,
        (void*)&bias, (void*)&lin, (void*)&hx, (void*)&cx,
        (void*)&hxAll, (void*)&bar };
    hipLaunchCooperativeKernel((const void*)k_loop, dim3(NBLK), dim3(512),
                               kargs, 0, stream);

    // batched logits: (NS*NB x NV), K=512
    k_logits<<<dim3(38 * 157), 256, 0, stream>>>(hxAll, fcWb, fc_b, out);
}

// Round 5
// 787.458 us; speedup vs baseline: 1.8737x; 1.8737x over previous
//
#include <hip/hip_runtime.h>
#include <hip/hip_bf16.h>
#include <math.h>

#define NB 128
#define NT 20
#define NS 19
#define NR 49
#define NV 10000
#define NE 512
#define NH 512
#define NFD 512
#define NA 256
#define NG 2048
#define NK2 1024   // gates GEMM K after emb-hoist: [ctx | hx]

typedef __bf16 bf16_t;
typedef bf16_t bf16x8 __attribute__((ext_vector_type(8)));
typedef float f32x4 __attribute__((ext_vector_type(4)));

__device__ __forceinline__ float sigm(float x) { return 1.f / (1.f + expf(-x)); }

__device__ __forceinline__ void cvt8(bf16_t* d, const float* s) {
    float4 a = *(const float4*)s;
    float4 b = *(const float4*)(s + 4);
    bf16x8 v;
    v[0] = (bf16_t)a.x; v[1] = (bf16_t)a.y; v[2] = (bf16_t)a.z; v[3] = (bf16_t)a.w;
    v[4] = (bf16_t)b.x; v[5] = (bf16_t)b.y; v[6] = (bf16_t)b.z; v[7] = (bf16_t)b.w;
    *(bf16x8*)d = v;
}

// ------------------------------------------------------------------
// k_prep: flat region-dispatch, 8 contiguous dest elems per thread.
// granules: fcWb 640000 | Wcat2 262144 | Wxg 131072 | W_hb 16384
//           Wfb 16384 | featb 401408 | linx 155648 | bias 256
//           hx0 8192 | cx0 8192   => total 1,639,680 = 6405 blocks
// ------------------------------------------------------------------
__global__ __launch_bounds__(256) void k_prep(
    const float* __restrict__ fc_W, const float* __restrict__ W_ih,
    const float* __restrict__ W_hh, const float* __restrict__ W_h,
    const float* __restrict__ W_f, const float* __restrict__ features,
    const float* __restrict__ emb, const int* __restrict__ captions,
    const float* __restrict__ b_ih, const float* __restrict__ b_hh,
    bf16_t* __restrict__ fcWb, bf16_t* __restrict__ Wcat2,
    bf16_t* __restrict__ Wxg, bf16_t* __restrict__ W_hb,
    bf16_t* __restrict__ Wfb, bf16_t* __restrict__ featb,
    bf16_t* __restrict__ linx, float* __restrict__ bias,
    float* __restrict__ hx, float* __restrict__ cx)
{
    int g = blockIdx.x * 256 + threadIdx.x;
    if (g < 640000) { int idx = g * 8; cvt8(fcWb + idx, fc_W + idx); return; }
    g -= 640000;
    if (g < 262144) {   // Wcat2[2048][1024] = [Wc | Whh], row n'=4h+g
        int idx = g * 8;
        int row = idx >> 10, col = idx & 1023;
        int orig = (row & 3) * NH + (row >> 2);
        const float* src = (col < 512) ? (W_ih + (size_t)orig * 1024 + 512 + col)
                                       : (W_hh + (size_t)orig * 512 + (col - 512));
        cvt8(Wcat2 + idx, src);
        return;
    }
    g -= 262144;
    if (g < 131072) {   // Wxg[2048][512] = x-part, row n'=4h+g
        int idx = g * 8;
        int row = idx >> 9, col = idx & 511;
        int orig = (row & 3) * NH + (row >> 2);
        cvt8(Wxg + idx, W_ih + (size_t)orig * 1024 + col);
        return;
    }
    g -= 131072;
    if (g < 16384) { int idx = g * 8; cvt8(W_hb + idx, W_h + idx); return; }
    g -= 16384;
    if (g < 16384) { int idx = g * 8; cvt8(Wfb + idx, W_f + idx); return; }
    g -= 16384;
    if (g < 401408) { int idx = g * 8; cvt8(featb + idx, features + idx); return; }
    g -= 401408;
    if (g < 155648) {   // linx[2432][512]: emb gather, row = t*128+b
        int idx = g * 8;
        int row = idx >> 9, col = idx & 511;
        int t = row >> 7, b = row & 127;
        int cap = captions[b * NT + t];
        cvt8(linx + idx, emb + (size_t)cap * NE + col);
        return;
    }
    g -= 155648;
    if (g < 256) {      // bias reorder (f32)
        int n0 = g * 8;
        #pragma unroll
        for (int i = 0; i < 8; ++i) {
            int n = n0 + i, h = n >> 2, gg = n & 3;
            int orig = gg * NH + h;
            bias[n] = b_ih[orig] + b_hh[orig];
        }
        return;
    }
    g -= 256;
    float4 z = make_float4(0.f, 0.f, 0.f, 0.f);
    if (g < 8192) { *(float4*)(hx + g * 8) = z; *(float4*)(hx + g * 8 + 4) = z; return; }
    g -= 8192;
    if (g < 8192) { *(float4*)(cx + g * 8) = z; *(float4*)(cx + g * 8 + 4) = z; }
}

// ------------------------------------------------------------------
// generic bf16 MFMA GEMM-NT: C[M,N] = A[M,K] @ B[N,K]^T (+bias)
// tile 64x64, BK=64, 4 waves. Cb!=null -> bf16 output, else f32 to Cf.
// ------------------------------------------------------------------
__global__ __launch_bounds__(256) void gemm_bf16_nt(
    const bf16_t* __restrict__ Am, const bf16_t* __restrict__ Bm,
    const float* __restrict__ bias, float* __restrict__ Cf,
    bf16_t* __restrict__ Cb, int M, int N, int K, int ldc)
{
    __shared__ uint4 AsU[512];
    __shared__ uint4 BsU[512];
    int tid = threadIdx.x;
    int m0 = blockIdx.x * 64, n0 = blockIdx.y * 64;
    int nk = K >> 6;

    int rowS = tid >> 3, slotS = tid & 7;
    int wr0 = rowS * 8 + (slotS ^ (rowS & 7));
    int rowS2 = rowS + 32;
    int wr1 = rowS2 * 8 + (slotS ^ (rowS2 & 7));

    const uint4* pA = (const uint4*)(Am + (size_t)(m0 + rowS) * K) + slotS;
    size_t aStep = (size_t)4 * K;
    int nrow0 = n0 + rowS, nrow1 = n0 + rowS2;
    bool bv0 = nrow0 < N, bv1 = nrow1 < N;
    const uint4* pB0 = (const uint4*)(Bm + (size_t)nrow0 * K) + slotS;
    const uint4* pB1 = (const uint4*)(Bm + (size_t)nrow1 * K) + slotS;
    uint4 zz = make_uint4(0, 0, 0, 0);

    int w = tid >> 6, lane = tid & 63;
    int wm = w >> 1, wn = w & 1;
    int lr = lane & 15, lg = lane >> 4;
    int ra[2][2], rb[2][2];
    #pragma unroll
    for (int i = 0; i < 2; ++i)
        #pragma unroll
        for (int kk = 0; kk < 2; ++kk) {
            int rA = wm * 32 + i * 16 + lr;
            int rB = wn * 32 + i * 16 + lr;
            int s = kk * 4 + lg;
            ra[i][kk] = rA * 8 + (s ^ (rA & 7));
            rb[i][kk] = rB * 8 + (s ^ (rB & 7));
        }

    f32x4 acc00 = {}, acc01 = {}, acc10 = {}, acc11 = {};
    uint4 a0 = pA[0], a1 = pA[aStep];
    uint4 b0 = bv0 ? pB0[0] : zz;
    uint4 b1 = bv1 ? pB1[0] : zz;
    pA += 8; pB0 += 8; pB1 += 8;

    #pragma unroll 1
    for (int kt = 0; kt < nk; ++kt) {
        __syncthreads();
        AsU[wr0] = a0; AsU[wr1] = a1;
        BsU[wr0] = b0; BsU[wr1] = b1;
        if (kt + 1 < nk) {
            a0 = pA[0]; a1 = pA[aStep];
            b0 = bv0 ? pB0[0] : zz;
            b1 = bv1 ? pB1[0] : zz;
            pA += 8; pB0 += 8; pB1 += 8;
        }
        __syncthreads();
        const bf16x8* Af = (const bf16x8*)AsU;
        const bf16x8* Bf = (const bf16x8*)BsU;
        #pragma unroll
        for (int kk = 0; kk < 2; ++kk) {
            bf16x8 fa0 = Af[ra[0][kk]], fa1 = Af[ra[1][kk]];
            bf16x8 fb0 = Bf[rb[0][kk]], fb1 = Bf[rb[1][kk]];
            acc00 = __builtin_amdgcn_mfma_f32_16x16x32_bf16(fa0, fb0, acc00, 0, 0, 0);
            acc01 = __builtin_amdgcn_mfma_f32_16x16x32_bf16(fa0, fb1, acc01, 0, 0, 0);
            acc10 = __builtin_amdgcn_mfma_f32_16x16x32_bf16(fa1, fb0, acc10, 0, 0, 0);
            acc11 = __builtin_amdgcn_mfma_f32_16x16x32_bf16(fa1, fb1, acc11, 0, 0, 0);
        }
    }

    f32x4 av[2][2] = {{acc00, acc01}, {acc10, acc11}};
    #pragma unroll
    for (int i = 0; i < 2; ++i) {
        int mbase = m0 + wm * 32 + i * 16 + lg * 4;
        #pragma unroll
        for (int j = 0; j < 2; ++j) {
            int n = n0 + wn * 32 + j * 16 + lr;
            if (n < N) {
                float bz = bias ? bias[n] : 0.f;
                #pragma unroll
                for (int r = 0; r < 4; ++r) {
                    float v = av[i][j][r] + bz;
                    if (Cb) Cb[(size_t)(mbase + r) * ldc + n] = (bf16_t)v;
                    else    Cf[(size_t)(mbase + r) * ldc + n] = v;
                }
            }
        }
    }
}

// ------------------------------------------------------------------
// attention: block b, 512 threads. Writes lin row = [ctx | hx] (bf16).
// ------------------------------------------------------------------
__global__ __launch_bounds__(512) void k_attn(
    const float* __restrict__ hx, const bf16_t* __restrict__ W_hb,
    const float* __restrict__ b_h, const float* __restrict__ fproj,
    const float* __restrict__ v_w, const bf16_t* __restrict__ featb,
    bf16_t* __restrict__ lin)
{
    int b = blockIdx.x;
    int tid = threadIdx.x;
    int w = tid >> 6, lane = tid & 63;
    __shared__ float hxs[NH];
    __shared__ float part[2][NA];
    __shared__ float salpha[64];

    hxs[tid] = hx[b * NH + tid];
    __syncthreads();

    {   // h = hx @ W_h^T : thread (q = tid>>8, a = tid&255), half-K dot
        int a = tid & 255, q = tid >> 8;
        const bf16x8* wrow = (const bf16x8*)(W_hb + (size_t)a * NH + q * 256);
        const float* hq = hxs + q * 256;
        float p = 0.f;
        #pragma unroll
        for (int c = 0; c < 32; ++c) {
            bf16x8 wv = wrow[c];
            int k = c * 8;
            p += hq[k+0]*(float)wv[0] + hq[k+1]*(float)wv[1]
               + hq[k+2]*(float)wv[2] + hq[k+3]*(float)wv[3]
               + hq[k+4]*(float)wv[4] + hq[k+5]*(float)wv[5]
               + hq[k+6]*(float)wv[6] + hq[k+7]*(float)wv[7];
        }
        part[q][a] = p;
    }
    __syncthreads();

    {   // scores: 8 waves strided over r
        for (int r = w; r < NR; r += 8) {
            const float* fp = fproj + ((size_t)b * NR + r) * NA;
            float s = 0.f;
            #pragma unroll
            for (int j = 0; j < 4; ++j) {
                int aa = lane + 64 * j;
                float hv = part[0][aa] + part[1][aa] + b_h[aa];
                s += tanhf(hv + fp[aa]) * v_w[aa];
            }
            #pragma unroll
            for (int off = 32; off; off >>= 1) s += __shfl_xor(s, off);
            if (lane == 0) salpha[r] = s;
        }
    }
    __syncthreads();

    if (tid < 64) {   // softmax over R=49 in wave 0
        float v = (tid < NR) ? salpha[tid] : -INFINITY;
        float m = v;
        #pragma unroll
        for (int off = 32; off; off >>= 1) m = fmaxf(m, __shfl_xor(m, off));
        float e = (tid < NR) ? expf(v - m) : 0.f;
        float ssum = e;
        #pragma unroll
        for (int off = 32; off; off >>= 1) ssum += __shfl_xor(ssum, off);
        if (tid < NR) salpha[tid] = e / ssum;
    }
    __syncthreads();

    {   // context + [ctx | hx] row
        bf16_t* lrow = lin + (size_t)b * NK2;
        float c = 0.f;
        #pragma unroll 7
        for (int r = 0; r < NR; ++r)
            c += salpha[r] * (float)featb[((size_t)b * NR + r) * NFD + tid];
        lrow[tid] = (bf16_t)c;
        lrow[NFD + tid] = (bf16_t)hxs[tid];
    }
}

// ------------------------------------------------------------------
// fused step: gates GEMM (128 x 2048 x 1024) + LSTM epilogue.
// gates = lin@Wcat2^T + pre_x[t] + bias. grid (2,32).
// ------------------------------------------------------------------
__global__ __launch_bounds__(256) void k_step(
    const bf16_t* __restrict__ lin, const bf16_t* __restrict__ Wcat2,
    const bf16_t* __restrict__ pre_x, const float* __restrict__ bias,
    float* __restrict__ hx, float* __restrict__ cx,
    bf16_t* __restrict__ hxAll, int t)
{
    __shared__ __align__(16) char smem[16640];
    uint4* AsU = (uint4*)smem;
    uint4* BsU = AsU + 512;

    int tid = threadIdx.x;
    int m0 = blockIdx.x * 64, n0 = blockIdx.y * 64;

    int rowS = tid >> 3, slotS = tid & 7;
    int wr0 = rowS * 8 + (slotS ^ (rowS & 7));
    int rowS2 = rowS + 32;
    int wr1 = rowS2 * 8 + (slotS ^ (rowS2 & 7));

    const uint4* pA = (const uint4*)(lin + (size_t)(m0 + rowS) * NK2) + slotS;
    const uint4* pB0 = (const uint4*)(Wcat2 + (size_t)(n0 + rowS) * NK2) + slotS;
    const uint4* pB1 = (const uint4*)(Wcat2 + (size_t)(n0 + rowS2) * NK2) + slotS;
    size_t aStep = (size_t)4 * NK2;

    int w = tid >> 6, lane = tid & 63;
    int wm = w >> 1, wn = w & 1;
    int lr = lane & 15, lg = lane >> 4;
    int ra[2][2], rb[2][2];
    #pragma unroll
    for (int i = 0; i < 2; ++i)
        #pragma unroll
        for (int kk = 0; kk < 2; ++kk) {
            int rA = wm * 32 + i * 16 + lr;
            int rB = wn * 32 + i * 16 + lr;
            int s = kk * 4 + lg;
            ra[i][kk] = rA * 8 + (s ^ (rA & 7));
            rb[i][kk] = rB * 8 + (s ^ (rB & 7));
        }

    f32x4 acc00 = {}, acc01 = {}, acc10 = {}, acc11 = {};
    uint4 a0 = pA[0], a1 = pA[aStep];
    uint4 b0 = pB0[0], b1 = pB1[0];
    pA += 8; pB0 += 8; pB1 += 8;

    #pragma unroll 1
    for (int kt = 0; kt < NK2 / 64; ++kt) {
        __syncthreads();
        AsU[wr0] = a0; AsU[wr1] = a1;
        BsU[wr0] = b0; BsU[wr1] = b1;
        if (kt + 1 < NK2 / 64) {
            a0 = pA[0]; a1 = pA[aStep];
            b0 = pB0[0]; b1 = pB1[0];
            pA += 8; pB0 += 8; pB1 += 8;
        }
        __syncthreads();
        const bf16x8* Af = (const bf16x8*)AsU;
        const bf16x8* Bf = (const bf16x8*)BsU;
        #pragma unroll
        for (int kk = 0; kk < 2; ++kk) {
            bf16x8 fa0 = Af[ra[0][kk]], fa1 = Af[ra[1][kk]];
            bf16x8 fb0 = Bf[rb[0][kk]], fb1 = Bf[rb[1][kk]];
            acc00 = __builtin_amdgcn_mfma_f32_16x16x32_bf16(fa0, fb0, acc00, 0, 0, 0);
            acc01 = __builtin_amdgcn_mfma_f32_16x16x32_bf16(fa0, fb1, acc01, 0, 0, 0);
            acc10 = __builtin_amdgcn_mfma_f32_16x16x32_bf16(fa1, fb0, acc10, 0, 0, 0);
            acc11 = __builtin_amdgcn_mfma_f32_16x16x32_bf16(fa1, fb1, acc11, 0, 0, 0);
        }
    }

    __syncthreads();
    float* Ct = (float*)smem;   // [64][65]
    f32x4 av[2][2] = {{acc00, acc01}, {acc10, acc11}};
    #pragma unroll
    for (int i = 0; i < 2; ++i)
        #pragma unroll
        for (int j = 0; j < 2; ++j) {
            int mloc = wm * 32 + i * 16 + lg * 4;
            int nloc = wn * 32 + j * 16 + lr;
            #pragma unroll
            for (int r = 0; r < 4; ++r)
                Ct[(mloc + r) * 65 + nloc] = av[i][j][r];
        }
    __syncthreads();

    int hloc = tid & 15;
    int h = (n0 >> 2) + hloc;
    #pragma unroll
    for (int q = 0; q < 4; ++q) {
        int m = (tid >> 4) + q * 16;
        int bb = m0 + m;
        const float* crow = Ct + m * 65 + hloc * 4;
        const float* brow = bias + n0 + hloc * 4;
        const bf16_t* prow = pre_x + ((size_t)t * NB + bb) * NG + n0 + hloc * 4;
        float gi = crow[0] + brow[0] + (float)prow[0];
        float gf = crow[1] + brow[1] + (float)prow[1];
        float gg = crow[2] + brow[2] + (float)prow[2];
        float go = crow[3] + brow[3] + (float)prow[3];
        size_t idx = (size_t)bb * NH + h;
        float c = sigm(gf) * cx[idx] + sigm(gi) * tanhf(gg);
        float hn = sigm(go) * tanhf(c);
        cx[idx] = c;
        hx[idx] = hn;
        hxAll[((size_t)t * NB + bb) * NH + h] = (bf16_t)hn;
    }
}

// ------------------------------------------------------------------
// batched logits GEMM, 128x128 tile, 4 waves of 64x64, XCD swizzle.
// A = hxAll [2432, 512] bf16, B = fcWb [10000, 512].
// C row m (m = t*128+b) -> out[(b*19+t)*10000 + n]. grid 19*79 = 1501.
// ------------------------------------------------------------------
__global__ __launch_bounds__(256) void k_logits(
    const bf16_t* __restrict__ hxAll, const bf16_t* __restrict__ fcWb,
    const float* __restrict__ fc_b, float* __restrict__ out)
{
    const int NWG = 19 * 79, Q = NWG / 8, R = NWG % 8;
    int bid = blockIdx.x;
    int xcd = bid & 7, loc = bid >> 3;
    int swz = (xcd < R ? xcd * (Q + 1) : R * (Q + 1) + (xcd - R) * Q) + loc;
    int m0 = (swz % 19) * 128;
    int n0 = (swz / 19) * 128;

    __shared__ uint4 AsU[1024];   // 128 rows x 8 slots (16B)
    __shared__ uint4 BsU[1024];
    int tid = threadIdx.x;

    int rowS = tid >> 3, slotS = tid & 7;
    int wrr[4];
    #pragma unroll
    for (int j = 0; j < 4; ++j) {
        int rj = rowS + 32 * j;
        wrr[j] = rj * 8 + (slotS ^ (rj & 7));
    }

    const uint4* pA = (const uint4*)(hxAll + (size_t)(m0 + rowS) * NH) + slotS;
    const uint4* pB = (const uint4*)(fcWb + (size_t)(n0 + rowS) * NH) + slotS;
    size_t step32 = (size_t)32 * (NH / 8);       // 32 rows in uint4 units
    bool bvv[4];
    #pragma unroll
    for (int j = 0; j < 4; ++j) bvv[j] = (n0 + rowS + 32 * j) < NV;
    uint4 zz = make_uint4(0, 0, 0, 0);

    int w = tid >> 6, lane = tid & 63;
    int wm = w >> 1, wn = w & 1;
    int lr = lane & 15, lg = lane >> 4;
    int ra[4][2], rb[4][2];
    #pragma unroll
    for (int i = 0; i < 4; ++i)
        #pragma unroll
        for (int kk = 0; kk < 2; ++kk) {
            int rA = wm * 64 + i * 16 + lr;
            int rB = wn * 64 + i * 16 + lr;
            int s = kk * 4 + lg;
            ra[i][kk] = rA * 8 + (s ^ (rA & 7));
            rb[i][kk] = rB * 8 + (s ^ (rB & 7));
        }

    f32x4 acc[4][4] = {};
    uint4 aR[4], bR[4];
    #pragma unroll
    for (int j = 0; j < 4; ++j) {
        aR[j] = pA[j * step32];
        bR[j] = bvv[j] ? pB[j * step32] : zz;
    }
    pA += 8; pB += 8;

    #pragma unroll 1
    for (int kt = 0; kt < NH / 64; ++kt) {
        __syncthreads();
        #pragma unroll
        for (int j = 0; j < 4; ++j) { AsU[wrr[j]] = aR[j]; BsU[wrr[j]] = bR[j]; }
        if (kt + 1 < NH / 64) {
            #pragma unroll
            for (int j = 0; j < 4; ++j) {
                aR[j] = pA[j * step32];
                bR[j] = bvv[j] ? pB[j * step32] : zz;
            }
            pA += 8; pB += 8;
        }
        __syncthreads();
        const bf16x8* Af = (const bf16x8*)AsU;
        const bf16x8* Bf = (const bf16x8*)BsU;
        #pragma unroll
        for (int kk = 0; kk < 2; ++kk) {
            bf16x8 fa[4], fb[4];
            #pragma unroll
            for (int i = 0; i < 4; ++i) { fa[i] = Af[ra[i][kk]]; fb[i] = Bf[rb[i][kk]]; }
            #pragma unroll
            for (int i = 0; i < 4; ++i)
                #pragma unroll
                for (int j = 0; j < 4; ++j)
                    acc[i][j] = __builtin_amdgcn_mfma_f32_16x16x32_bf16(fa[i], fb[j], acc[i][j], 0, 0, 0);
        }
    }

    #pragma unroll
    for (int i = 0; i < 4; ++i) {
        int mbase = m0 + wm * 64 + i * 16 + lg * 4;
        #pragma unroll
        for (int j = 0; j < 4; ++j) {
            int n = n0 + wn * 64 + j * 16 + lr;
            if (n < NV) {
                float bz = fc_b[n];
                #pragma unroll
                for (int r = 0; r < 4; ++r) {
                    int m = mbase + r;
                    int bb = m & 127, tt = m >> 7;
                    out[((size_t)bb * NS + tt) * NV + n] = acc[i][j][r] + bz;
                }
            }
        }
    }
}

// ------------------------------------------------------------------
extern "C" void kernel_launch(void* const* d_in, const int* in_sizes, int n_in,
                              void* d_out, int out_size, void* d_ws, size_t ws_size,
                              hipStream_t stream)
{
    const float* features = (const float*)d_in[0];
    const int*   captions = (const int*)d_in[1];
    const float* emb      = (const float*)d_in[2];
    const float* W_h      = (const float*)d_in[3];
    const float* b_h      = (const float*)d_in[4];
    const float* W_f      = (const float*)d_in[5];
    const float* b_f      = (const float*)d_in[6];
    const float* v_w      = (const float*)d_in[7];
    // d_in[8] = v_b : cancels in softmax
    const float* W_ih     = (const float*)d_in[9];
    const float* W_hh     = (const float*)d_in[10];
    const float* b_ih     = (const float*)d_in[11];
    const float* b_hh     = (const float*)d_in[12];
    const float* fc_W     = (const float*)d_in[13];
    const float* fc_b     = (const float*)d_in[14];
    float* out = (float*)d_out;

    char* base = (char*)d_ws;
    bf16_t* fcWb  = (bf16_t*)base;  base += (size_t)NV * NH * 2;
    bf16_t* Wcat2 = (bf16_t*)base;  base += (size_t)NG * NK2 * 2;
    bf16_t* Wxg   = (bf16_t*)base;  base += (size_t)NG * NE * 2;
    bf16_t* W_hb  = (bf16_t*)base;  base += (size_t)NA * NH * 2;
    bf16_t* Wfb   = (bf16_t*)base;  base += (size_t)NA * NFD * 2;
    bf16_t* featb = (bf16_t*)base;  base += (size_t)NB * NR * NFD * 2;
    bf16_t* linx  = (bf16_t*)base;  base += (size_t)NS * NB * NE * 2;
    bf16_t* pre_x = (bf16_t*)base;  base += (size_t)NS * NB * NG * 2;
    bf16_t* lin   = (bf16_t*)base;  base += (size_t)NB * NK2 * 2;
    bf16_t* hxAll = (bf16_t*)base;  base += (size_t)NS * NB * NH * 2;
    float*  fproj = (float*)base;   base += (size_t)NB * NR * NA * 4;
    float*  bias  = (float*)base;   base += (size_t)NG * 4;
    float*  hx    = (float*)base;   base += (size_t)NB * NH * 4;
    float*  cx    = (float*)base;   base += (size_t)NB * NH * 4;
    // total ~45.7 MB

    k_prep<<<dim3(6405), 256, 0, stream>>>(
        fc_W, W_ih, W_hh, W_h, W_f, features, emb, captions, b_ih, b_hh,
        fcWb, Wcat2, Wxg, W_hb, Wfb, featb, linx, bias, hx, cx);

    // f_proj = features @ W_f^T + b_f : (6272 x 256), K=512, f32 out
    gemm_bf16_nt<<<dim3(98, 4), 256, 0, stream>>>(
        featb, Wfb, b_f, fproj, (bf16_t*)0, NB * NR, NA, NFD, NA);

    // pre_x = linx @ Wxg^T : (2432 x 2048), K=512, bf16 out, no bias
    gemm_bf16_nt<<<dim3(38, 32), 256, 0, stream>>>(
        linx, Wxg, (const float*)0, (float*)0, pre_x, NS * NB, NG, NE, NG);

    for (int t = 0; t < NS; ++t) {
        k_attn<<<dim3(NB), 512, 0, stream>>>(
            hx, W_hb, b_h, fproj, v_w, featb, lin);
        k_step<<<dim3(2, 32), 256, 0, stream>>>(
            lin, Wcat2, pre_x, bias, hx, cx, hxAll, t);
    }

    // batched logits: (2432 x 10000), K=512, 128x128 tiles
    k_logits<<<dim3(19 * 79), 256, 0, stream>>>(hxAll, fcWb, fc_b, out);
}

// Round 6
// 755.295 us; speedup vs baseline: 1.9535x; 1.0426x over previous
//
#include <hip/hip_runtime.h>
#include <hip/hip_bf16.h>
#include <math.h>

#define NB 128
#define NT 20
#define NS 19
#define NR 49
#define NV 10000
#define NE 512
#define NH 512
#define NFD 512
#define NA 256
#define NG 2048
#define NK2 1024   // gates GEMM K after emb-hoist: [ctx | hx]

typedef __bf16 bf16_t;
typedef bf16_t bf16x8 __attribute__((ext_vector_type(8)));
typedef float f32x4 __attribute__((ext_vector_type(4)));

__device__ __forceinline__ float sigm(float x) { return 1.f / (1.f + expf(-x)); }

__device__ __forceinline__ void cvt8(bf16_t* d, const float* s) {
    float4 a = *(const float4*)s;
    float4 b = *(const float4*)(s + 4);
    bf16x8 v;
    v[0] = (bf16_t)a.x; v[1] = (bf16_t)a.y; v[2] = (bf16_t)a.z; v[3] = (bf16_t)a.w;
    v[4] = (bf16_t)b.x; v[5] = (bf16_t)b.y; v[6] = (bf16_t)b.z; v[7] = (bf16_t)b.w;
    *(bf16x8*)d = v;
}

// ------------------------------------------------------------------
// k_prep: flat region-dispatch, 8 contiguous dest elems per thread.
// granules: fcWb 640000 | Wcat2 262144 | Wxg 131072 | W_hb 16384
//  Wfb 16384 | featb 401408 | linx 155648 | bias 256 | bfh 32
//  hx0 8192 | cx0 8192  => 1,639,712 granules = 6406 blocks x 256
// ------------------------------------------------------------------
__global__ __launch_bounds__(256) void k_prep(
    const float* __restrict__ fc_W, const float* __restrict__ W_ih,
    const float* __restrict__ W_hh, const float* __restrict__ W_h,
    const float* __restrict__ W_f, const float* __restrict__ features,
    const float* __restrict__ emb, const int* __restrict__ captions,
    const float* __restrict__ b_ih, const float* __restrict__ b_hh,
    const float* __restrict__ b_f, const float* __restrict__ b_h,
    bf16_t* __restrict__ fcWb, bf16_t* __restrict__ Wcat2,
    bf16_t* __restrict__ Wxg, bf16_t* __restrict__ W_hb,
    bf16_t* __restrict__ Wfb, bf16_t* __restrict__ featb,
    bf16_t* __restrict__ linx, float* __restrict__ bias,
    float* __restrict__ bfh, float* __restrict__ hx, float* __restrict__ cx)
{
    int g = blockIdx.x * 256 + threadIdx.x;
    if (g < 640000) { int idx = g * 8; cvt8(fcWb + idx, fc_W + idx); return; }
    g -= 640000;
    if (g < 262144) {   // Wcat2[2048][1024] = [Wc | Whh], row n'=4h+g
        int idx = g * 8;
        int row = idx >> 10, col = idx & 1023;
        int orig = (row & 3) * NH + (row >> 2);
        const float* src = (col < 512) ? (W_ih + (size_t)orig * 1024 + 512 + col)
                                       : (W_hh + (size_t)orig * 512 + (col - 512));
        cvt8(Wcat2 + idx, src);
        return;
    }
    g -= 262144;
    if (g < 131072) {   // Wxg[2048][512] = x-part, row n'=4h+g
        int idx = g * 8;
        int row = idx >> 9, col = idx & 511;
        int orig = (row & 3) * NH + (row >> 2);
        cvt8(Wxg + idx, W_ih + (size_t)orig * 1024 + col);
        return;
    }
    g -= 131072;
    if (g < 16384) { int idx = g * 8; cvt8(W_hb + idx, W_h + idx); return; }
    g -= 16384;
    if (g < 16384) { int idx = g * 8; cvt8(Wfb + idx, W_f + idx); return; }
    g -= 16384;
    if (g < 401408) { int idx = g * 8; cvt8(featb + idx, features + idx); return; }
    g -= 401408;
    if (g < 155648) {   // linx[2432][512]: emb gather, row = t*128+b
        int idx = g * 8;
        int row = idx >> 9, col = idx & 511;
        int t = row >> 7, b = row & 127;
        int cap = captions[b * NT + t];
        cvt8(linx + idx, emb + (size_t)cap * NE + col);
        return;
    }
    g -= 155648;
    if (g < 256) {      // bias reorder (f32)
        int n0 = g * 8;
        #pragma unroll
        for (int i = 0; i < 8; ++i) {
            int n = n0 + i, h = n >> 2, gg = n & 3;
            int orig = gg * NH + h;
            bias[n] = b_ih[orig] + b_hh[orig];
        }
        return;
    }
    g -= 256;
    if (g < 32) {       // bfh = b_f + b_h (folded into fproj)
        int n0 = g * 8;
        #pragma unroll
        for (int i = 0; i < 8; ++i) bfh[n0 + i] = b_f[n0 + i] + b_h[n0 + i];
        return;
    }
    g -= 32;
    float4 z = make_float4(0.f, 0.f, 0.f, 0.f);
    if (g < 8192) { *(float4*)(hx + g * 8) = z; *(float4*)(hx + g * 8 + 4) = z; return; }
    g -= 8192;
    if (g < 8192) { *(float4*)(cx + g * 8) = z; *(float4*)(cx + g * 8 + 4) = z; }
}

// ------------------------------------------------------------------
// generic bf16 MFMA GEMM-NT: C[M,N] = A[M,K] @ B[N,K]^T (+bias)
// tile 64x64, BK=64, 4 waves. Cb!=null -> bf16 output, else f32 to Cf.
// ------------------------------------------------------------------
__global__ __launch_bounds__(256) void gemm_bf16_nt(
    const bf16_t* __restrict__ Am, const bf16_t* __restrict__ Bm,
    const float* __restrict__ bias, float* __restrict__ Cf,
    bf16_t* __restrict__ Cb, int M, int N, int K, int ldc)
{
    __shared__ uint4 AsU[512];
    __shared__ uint4 BsU[512];
    int tid = threadIdx.x;
    int m0 = blockIdx.x * 64, n0 = blockIdx.y * 64;
    int nk = K >> 6;

    int rowS = tid >> 3, slotS = tid & 7;
    int wr0 = rowS * 8 + (slotS ^ (rowS & 7));
    int rowS2 = rowS + 32;
    int wr1 = rowS2 * 8 + (slotS ^ (rowS2 & 7));

    const uint4* pA = (const uint4*)(Am + (size_t)(m0 + rowS) * K) + slotS;
    size_t aStep = (size_t)4 * K;
    int nrow0 = n0 + rowS, nrow1 = n0 + rowS2;
    bool bv0 = nrow0 < N, bv1 = nrow1 < N;
    const uint4* pB0 = (const uint4*)(Bm + (size_t)nrow0 * K) + slotS;
    const uint4* pB1 = (const uint4*)(Bm + (size_t)nrow1 * K) + slotS;
    uint4 zz = make_uint4(0, 0, 0, 0);

    int w = tid >> 6, lane = tid & 63;
    int wm = w >> 1, wn = w & 1;
    int lr = lane & 15, lg = lane >> 4;
    int ra[2][2], rb[2][2];
    #pragma unroll
    for (int i = 0; i < 2; ++i)
        #pragma unroll
        for (int kk = 0; kk < 2; ++kk) {
            int rA = wm * 32 + i * 16 + lr;
            int rB = wn * 32 + i * 16 + lr;
            int s = kk * 4 + lg;
            ra[i][kk] = rA * 8 + (s ^ (rA & 7));
            rb[i][kk] = rB * 8 + (s ^ (rB & 7));
        }

    f32x4 acc00 = {}, acc01 = {}, acc10 = {}, acc11 = {};
    uint4 a0 = pA[0], a1 = pA[aStep];
    uint4 b0 = bv0 ? pB0[0] : zz;
    uint4 b1 = bv1 ? pB1[0] : zz;
    pA += 8; pB0 += 8; pB1 += 8;

    #pragma unroll 1
    for (int kt = 0; kt < nk; ++kt) {
        __syncthreads();
        AsU[wr0] = a0; AsU[wr1] = a1;
        BsU[wr0] = b0; BsU[wr1] = b1;
        if (kt + 1 < nk) {
            a0 = pA[0]; a1 = pA[aStep];
            b0 = bv0 ? pB0[0] : zz;
            b1 = bv1 ? pB1[0] : zz;
            pA += 8; pB0 += 8; pB1 += 8;
        }
        __syncthreads();
        const bf16x8* Af = (const bf16x8*)AsU;
        const bf16x8* Bf = (const bf16x8*)BsU;
        #pragma unroll
        for (int kk = 0; kk < 2; ++kk) {
            bf16x8 fa0 = Af[ra[0][kk]], fa1 = Af[ra[1][kk]];
            bf16x8 fb0 = Bf[rb[0][kk]], fb1 = Bf[rb[1][kk]];
            acc00 = __builtin_amdgcn_mfma_f32_16x16x32_bf16(fa0, fb0, acc00, 0, 0, 0);
            acc01 = __builtin_amdgcn_mfma_f32_16x16x32_bf16(fa0, fb1, acc01, 0, 0, 0);
            acc10 = __builtin_amdgcn_mfma_f32_16x16x32_bf16(fa1, fb0, acc10, 0, 0, 0);
            acc11 = __builtin_amdgcn_mfma_f32_16x16x32_bf16(fa1, fb1, acc11, 0, 0, 0);
        }
    }

    f32x4 av[2][2] = {{acc00, acc01}, {acc10, acc11}};
    #pragma unroll
    for (int i = 0; i < 2; ++i) {
        int mbase = m0 + wm * 32 + i * 16 + lg * 4;
        #pragma unroll
        for (int j = 0; j < 2; ++j) {
            int n = n0 + wn * 32 + j * 16 + lr;
            if (n < N) {
                float bz = bias ? bias[n] : 0.f;
                #pragma unroll
                for (int r = 0; r < 4; ++r) {
                    float v = av[i][j][r] + bz;
                    if (Cb) Cb[(size_t)(mbase + r) * ldc + n] = (bf16_t)v;
                    else    Cf[(size_t)(mbase + r) * ldc + n] = v;
                }
            }
        }
    }
}

// ------------------------------------------------------------------
// attention: block b, 512 threads. fproj is bf16 with b_f+b_h folded.
// Writes lin row = [ctx | hx] (bf16).
// ------------------------------------------------------------------
__global__ __launch_bounds__(512) void k_attn(
    const float* __restrict__ hx, const bf16_t* __restrict__ W_hb,
    const bf16_t* __restrict__ fprojb, const float* __restrict__ v_w,
    const bf16_t* __restrict__ featb, bf16_t* __restrict__ lin)
{
    int b = blockIdx.x;
    int tid = threadIdx.x;
    int w = tid >> 6, lane = tid & 63;
    __shared__ float hxs[NH];
    __shared__ float part[2][NA];
    __shared__ float salpha[64];

    hxs[tid] = hx[b * NH + tid];
    __syncthreads();

    {   // h = hx @ W_h^T : thread (q = tid>>8, a = tid&255), half-K dot
        int a = tid & 255, q = tid >> 8;
        const bf16x8* wrow = (const bf16x8*)(W_hb + (size_t)a * NH + q * 256);
        const float* hq = hxs + q * 256;
        float p = 0.f;
        #pragma unroll
        for (int c = 0; c < 32; ++c) {
            bf16x8 wv = wrow[c];
            int k = c * 8;
            p += hq[k+0]*(float)wv[0] + hq[k+1]*(float)wv[1]
               + hq[k+2]*(float)wv[2] + hq[k+3]*(float)wv[3]
               + hq[k+4]*(float)wv[4] + hq[k+5]*(float)wv[5]
               + hq[k+6]*(float)wv[6] + hq[k+7]*(float)wv[7];
        }
        part[q][a] = p;
    }
    __syncthreads();

    {   // scores: 8 waves strided over r
        for (int r = w; r < NR; r += 8) {
            const bf16_t* fp = fprojb + ((size_t)b * NR + r) * NA;
            float s = 0.f;
            #pragma unroll
            for (int j = 0; j < 4; ++j) {
                int aa = lane + 64 * j;
                float hv = part[0][aa] + part[1][aa];
                s += tanhf(hv + (float)fp[aa]) * v_w[aa];
            }
            #pragma unroll
            for (int off = 32; off; off >>= 1) s += __shfl_xor(s, off);
            if (lane == 0) salpha[r] = s;
        }
    }
    __syncthreads();

    if (tid < 64) {   // softmax over R=49 in wave 0
        float v = (tid < NR) ? salpha[tid] : -INFINITY;
        float m = v;
        #pragma unroll
        for (int off = 32; off; off >>= 1) m = fmaxf(m, __shfl_xor(m, off));
        float e = (tid < NR) ? expf(v - m) : 0.f;
        float ssum = e;
        #pragma unroll
        for (int off = 32; off; off >>= 1) ssum += __shfl_xor(ssum, off);
        if (tid < NR) salpha[tid] = e / ssum;
    }
    __syncthreads();

    {   // context + [ctx | hx] row
        bf16_t* lrow = lin + (size_t)b * NK2;
        float c = 0.f;
        #pragma unroll 7
        for (int r = 0; r < NR; ++r)
            c += salpha[r] * (float)featb[((size_t)b * NR + r) * NFD + tid];
        lrow[tid] = (bf16_t)c;
        lrow[NFD + tid] = (bf16_t)hxs[tid];
    }
}

// ------------------------------------------------------------------
// fused step: gates GEMM (128 x 2048 x 1024) + LSTM epilogue.
// grid (4,32): tile 32 batches x 64 gate-cols. 4 waves: wm=w&1 (m-half),
// wn=w>>1 (n-half); per wave 16x32 = 1 m-frag x 2 n-frags.
// gates = lin@Wcat2^T + pre_x[t] + bias.
// ------------------------------------------------------------------
__global__ __launch_bounds__(256) void k_step(
    const bf16_t* __restrict__ lin, const bf16_t* __restrict__ Wcat2,
    const bf16_t* __restrict__ pre_x, const float* __restrict__ bias,
    float* __restrict__ hx, float* __restrict__ cx,
    bf16_t* __restrict__ hxAll, int t)
{
    __shared__ __align__(16) char smem[12288];
    uint4* AsU = (uint4*)smem;          // [256]  32 rows x 8 slots
    uint4* BsU = AsU + 256;             // [512]  64 rows x 8 slots

    int tid = threadIdx.x;
    int m0 = blockIdx.x * 32, n0 = blockIdx.y * 64;

    int rowS = tid >> 3, slotS = tid & 7;     // rowS 0..31
    int wrA = rowS * 8 + (slotS ^ (rowS & 7));
    int rowB2 = rowS + 32;
    int wrB1 = rowB2 * 8 + (slotS ^ (rowB2 & 7));

    const uint4* pA  = (const uint4*)(lin   + (size_t)(m0 + rowS) * NK2) + slotS;
    const uint4* pB0 = (const uint4*)(Wcat2 + (size_t)(n0 + rowS) * NK2) + slotS;
    const uint4* pB1 = (const uint4*)(Wcat2 + (size_t)(n0 + rowB2) * NK2) + slotS;

    int w = tid >> 6, lane = tid & 63;
    int wm = w & 1, wn = w >> 1;
    int lr = lane & 15, lg = lane >> 4;
    int raI[2], rbI[2][2];
    #pragma unroll
    for (int kk = 0; kk < 2; ++kk) {
        int rA = wm * 16 + lr;
        int s = kk * 4 + lg;
        raI[kk] = rA * 8 + (s ^ (rA & 7));
        #pragma unroll
        for (int j = 0; j < 2; ++j) {
            int rB = wn * 32 + j * 16 + lr;
            rbI[j][kk] = rB * 8 + (s ^ (rB & 7));
        }
    }

    f32x4 acc0 = {}, acc1 = {};
    uint4 a0 = pA[0], b0 = pB0[0], b1 = pB1[0];
    pA += 8; pB0 += 8; pB1 += 8;

    #pragma unroll 1
    for (int kt = 0; kt < NK2 / 64; ++kt) {
        __syncthreads();
        AsU[wrA] = a0; BsU[wrA] = b0; BsU[wrB1] = b1;
        if (kt + 1 < NK2 / 64) {
            a0 = pA[0]; b0 = pB0[0]; b1 = pB1[0];
            pA += 8; pB0 += 8; pB1 += 8;
        }
        __syncthreads();
        const bf16x8* Af = (const bf16x8*)AsU;
        const bf16x8* Bf = (const bf16x8*)BsU;
        #pragma unroll
        for (int kk = 0; kk < 2; ++kk) {
            bf16x8 fa  = Af[raI[kk]];
            bf16x8 fb0 = Bf[rbI[0][kk]];
            bf16x8 fb1 = Bf[rbI[1][kk]];
            acc0 = __builtin_amdgcn_mfma_f32_16x16x32_bf16(fa, fb0, acc0, 0, 0, 0);
            acc1 = __builtin_amdgcn_mfma_f32_16x16x32_bf16(fa, fb1, acc1, 0, 0, 0);
        }
    }

    __syncthreads();
    float* Ct = (float*)smem;   // [32][65]
    {
        int crow = wm * 16 + lg * 4;
        #pragma unroll
        for (int r = 0; r < 4; ++r) {
            Ct[(crow + r) * 65 + wn * 32 + lr]      = acc0[r];
            Ct[(crow + r) * 65 + wn * 32 + 16 + lr] = acc1[r];
        }
    }
    __syncthreads();

    int hloc = tid & 15;
    int h = (n0 >> 2) + hloc;
    #pragma unroll
    for (int q = 0; q < 2; ++q) {
        int m = (tid >> 4) + q * 16;
        int bb = m0 + m;
        const float* crow = Ct + m * 65 + hloc * 4;
        const float* brow = bias + n0 + hloc * 4;
        const bf16_t* prow = pre_x + ((size_t)t * NB + bb) * NG + n0 + hloc * 4;
        float gi = crow[0] + brow[0] + (float)prow[0];
        float gf = crow[1] + brow[1] + (float)prow[1];
        float gg = crow[2] + brow[2] + (float)prow[2];
        float go = crow[3] + brow[3] + (float)prow[3];
        size_t idx = (size_t)bb * NH + h;
        float c = sigm(gf) * cx[idx] + sigm(gi) * tanhf(gg);
        float hn = sigm(go) * tanhf(c);
        cx[idx] = c;
        hx[idx] = hn;
        hxAll[((size_t)t * NB + bb) * NH + h] = (bf16_t)hn;
    }
}

// ------------------------------------------------------------------
// batched logits GEMM, 128x128 tile, XCD swizzle, LDS-staged COALESCED
// epilogue (4 chunks of 32 rows; each half-wave writes 512 B contiguous).
// A = hxAll [2432, 512] bf16, B = fcWb [10000, 512]. grid 19*79 = 1501.
// ------------------------------------------------------------------
__global__ __launch_bounds__(256) void k_logits(
    const bf16_t* __restrict__ hxAll, const bf16_t* __restrict__ fcWb,
    const float* __restrict__ fc_b, float* __restrict__ out)
{
    const int NWG = 19 * 79, Q = NWG / 8, R = NWG % 8;
    int bid = blockIdx.x;
    int xcd = bid & 7, loc = bid >> 3;
    int swz = (xcd < R ? xcd * (Q + 1) : R * (Q + 1) + (xcd - R) * Q) + loc;
    int m0 = (swz % 19) * 128;
    int n0 = (swz / 19) * 128;

    __shared__ uint4 AsU[1024];   // 128 rows x 8 slots (16B)
    __shared__ uint4 BsU[1024];
    int tid = threadIdx.x;

    int rowS = tid >> 3, slotS = tid & 7;
    int wrr[4];
    #pragma unroll
    for (int j = 0; j < 4; ++j) {
        int rj = rowS + 32 * j;
        wrr[j] = rj * 8 + (slotS ^ (rj & 7));
    }

    const uint4* pA = (const uint4*)(hxAll + (size_t)(m0 + rowS) * NH) + slotS;
    const uint4* pB = (const uint4*)(fcWb + (size_t)(n0 + rowS) * NH) + slotS;
    size_t step32 = (size_t)32 * (NH / 8);       // 32 rows in uint4 units
    bool bvv[4];
    #pragma unroll
    for (int j = 0; j < 4; ++j) bvv[j] = (n0 + rowS + 32 * j) < NV;
    uint4 zz = make_uint4(0, 0, 0, 0);

    int w = tid >> 6, lane = tid & 63;
    int wm = w >> 1, wn = w & 1;
    int lr = lane & 15, lg = lane >> 4;
    int ra[4][2], rb[4][2];
    #pragma unroll
    for (int i = 0; i < 4; ++i)
        #pragma unroll
        for (int kk = 0; kk < 2; ++kk) {
            int rA = wm * 64 + i * 16 + lr;
            int rB = wn * 64 + i * 16 + lr;
            int s = kk * 4 + lg;
            ra[i][kk] = rA * 8 + (s ^ (rA & 7));
            rb[i][kk] = rB * 8 + (s ^ (rB & 7));
        }

    f32x4 acc[4][4] = {};
    uint4 aR[4], bR[4];
    #pragma unroll
    for (int j = 0; j < 4; ++j) {
        aR[j] = pA[j * step32];
        bR[j] = bvv[j] ? pB[j * step32] : zz;
    }
    pA += 8; pB += 8;

    #pragma unroll 1
    for (int kt = 0; kt < NH / 64; ++kt) {
        __syncthreads();
        #pragma unroll
        for (int j = 0; j < 4; ++j) { AsU[wrr[j]] = aR[j]; BsU[wrr[j]] = bR[j]; }
        if (kt + 1 < NH / 64) {
            #pragma unroll
            for (int j = 0; j < 4; ++j) {
                aR[j] = pA[j * step32];
                bR[j] = bvv[j] ? pB[j * step32] : zz;
            }
            pA += 8; pB += 8;
        }
        __syncthreads();
        const bf16x8* Af = (const bf16x8*)AsU;
        const bf16x8* Bf = (const bf16x8*)BsU;
        #pragma unroll
        for (int kk = 0; kk < 2; ++kk) {
            bf16x8 fa[4], fb[4];
            #pragma unroll
            for (int i = 0; i < 4; ++i) { fa[i] = Af[ra[i][kk]]; fb[i] = Bf[rb[i][kk]]; }
            #pragma unroll
            for (int i = 0; i < 4; ++i)
                #pragma unroll
                for (int j = 0; j < 4; ++j)
                    acc[i][j] = __builtin_amdgcn_mfma_f32_16x16x32_bf16(fa[i], fb[j], acc[i][j], 0, 0, 0);
        }
    }

    // ---- LDS-staged coalesced epilogue: 4 chunks of 32 rows ----
    float* Ct = (float*)AsU;          // [32][132] f32 = 16.5 KB
    const int LDC = 132;
    int c4 = tid & 31;
    int n = n0 + c4 * 4;
    bool nok = n < NV;                // NV % 4 == 0 -> whole float4 valid
    #pragma unroll
    for (int c = 0; c < 4; ++c) {
        __syncthreads();
        if (wm == (c >> 1)) {
            #pragma unroll
            for (int ii = 0; ii < 2; ++ii) {
                int i = (c & 1) * 2 + ii;
                int rloc = ii * 16 + lg * 4;
                #pragma unroll
                for (int j = 0; j < 4; ++j) {
                    int col = wn * 64 + j * 16 + lr;
                    #pragma unroll
                    for (int r = 0; r < 4; ++r)
                        Ct[(rloc + r) * LDC + col] = acc[i][j][r];
                }
            }
        }
        __syncthreads();
        if (nok) {
            float4 bz = *(const float4*)(fc_b + n);
            #pragma unroll
            for (int p = 0; p < 4; ++p) {
                int rloc = p * 8 + (tid >> 5);
                int m = m0 + c * 32 + rloc;
                int bb = m & 127, tt = m >> 7;
                float4 v = *(float4*)(Ct + rloc * LDC + c4 * 4);
                v.x += bz.x; v.y += bz.y; v.z += bz.z; v.w += bz.w;
                *(float4*)(out + ((size_t)bb * NS + tt) * NV + n) = v;
            }
        }
    }
}

// ------------------------------------------------------------------
extern "C" void kernel_launch(void* const* d_in, const int* in_sizes, int n_in,
                              void* d_out, int out_size, void* d_ws, size_t ws_size,
                              hipStream_t stream)
{
    const float* features = (const float*)d_in[0];
    const int*   captions = (const int*)d_in[1];
    const float* emb      = (const float*)d_in[2];
    const float* W_h      = (const float*)d_in[3];
    const float* b_h      = (const float*)d_in[4];
    const float* W_f      = (const float*)d_in[5];
    const float* b_f      = (const float*)d_in[6];
    const float* v_w      = (const float*)d_in[7];
    // d_in[8] = v_b : cancels in softmax
    const float* W_ih     = (const float*)d_in[9];
    const float* W_hh     = (const float*)d_in[10];
    const float* b_ih     = (const float*)d_in[11];
    const float* b_hh     = (const float*)d_in[12];
    const float* fc_W     = (const float*)d_in[13];
    const float* fc_b     = (const float*)d_in[14];
    float* out = (float*)d_out;

    char* base = (char*)d_ws;
    bf16_t* fcWb   = (bf16_t*)base;  base += (size_t)NV * NH * 2;
    bf16_t* Wcat2  = (bf16_t*)base;  base += (size_t)NG * NK2 * 2;
    bf16_t* Wxg    = (bf16_t*)base;  base += (size_t)NG * NE * 2;
    bf16_t* W_hb   = (bf16_t*)base;  base += (size_t)NA * NH * 2;
    bf16_t* Wfb    = (bf16_t*)base;  base += (size_t)NA * NFD * 2;
    bf16_t* featb  = (bf16_t*)base;  base += (size_t)NB * NR * NFD * 2;
    bf16_t* linx   = (bf16_t*)base;  base += (size_t)NS * NB * NE * 2;
    bf16_t* pre_x  = (bf16_t*)base;  base += (size_t)NS * NB * NG * 2;
    bf16_t* lin    = (bf16_t*)base;  base += (size_t)NB * NK2 * 2;
    bf16_t* hxAll  = (bf16_t*)base;  base += (size_t)NS * NB * NH * 2;
    bf16_t* fprojb = (bf16_t*)base;  base += (size_t)NB * NR * NA * 2;
    float*  bias   = (float*)base;   base += (size_t)NG * 4;
    float*  bfh    = (float*)base;   base += (size_t)NA * 4;
    float*  hx     = (float*)base;   base += (size_t)NB * NH * 4;
    float*  cx     = (float*)base;   base += (size_t)NB * NH * 4;
    // total ~42.5 MB

    k_prep<<<dim3(6406), 256, 0, stream>>>(
        fc_W, W_ih, W_hh, W_h, W_f, features, emb, captions, b_ih, b_hh,
        b_f, b_h, fcWb, Wcat2, Wxg, W_hb, Wfb, featb, linx, bias, bfh, hx, cx);

    // f_proj = features @ W_f^T + (b_f + b_h) : (6272 x 256), K=512, bf16 out
    gemm_bf16_nt<<<dim3(98, 4), 256, 0, stream>>>(
        featb, Wfb, bfh, (float*)0, fprojb, NB * NR, NA, NFD, NA);

    // pre_x = linx @ Wxg^T : (2432 x 2048), K=512, bf16 out, no bias
    gemm_bf16_nt<<<dim3(38, 32), 256, 0, stream>>>(
        linx, Wxg, (const float*)0, (float*)0, pre_x, NS * NB, NG, NE, NG);

    for (int t = 0; t < NS; ++t) {
        k_attn<<<dim3(NB), 512, 0, stream>>>(
            hx, W_hb, fprojb, v_w, featb, lin);
        k_step<<<dim3(4, 32), 256, 0, stream>>>(
            lin, Wcat2, pre_x, bias, hx, cx, hxAll, t);
    }

    // batched logits: (2432 x 10000), K=512, 128x128 tiles
    k_logits<<<dim3(19 * 79), 256, 0, stream>>>(hxAll, fcWb, fc_b, out);
}

// Round 7
// 670.295 us; speedup vs baseline: 2.2012x; 1.1268x over previous
//
#include <hip/hip_runtime.h>
#include <hip/hip_bf16.h>
#include <math.h>

#define NB 128
#define NT 20
#define NS 19
#define NR 49
#define NV 10000
#define NE 512
#define NH 512
#define NFD 512
#define NA 256
#define NG 2048
#define NK2 1024   // gates GEMM K after emb-hoist: [ctx | hx]

typedef __bf16 bf16_t;
typedef bf16_t bf16x8 __attribute__((ext_vector_type(8)));
typedef float f32x4 __attribute__((ext_vector_type(4)));

__device__ __forceinline__ float sigm(float x) { return 1.f / (1.f + expf(-x)); }

__device__ __forceinline__ void cvt8(bf16_t* d, const float* s) {
    float4 a = *(const float4*)s;
    float4 b = *(const float4*)(s + 4);
    bf16x8 v;
    v[0] = (bf16_t)a.x; v[1] = (bf16_t)a.y; v[2] = (bf16_t)a.z; v[3] = (bf16_t)a.w;
    v[4] = (bf16_t)b.x; v[5] = (bf16_t)b.y; v[6] = (bf16_t)b.z; v[7] = (bf16_t)b.w;
    *(bf16x8*)d = v;
}

// ------------------------------------------------------------------
// k_prep: flat region-dispatch, 8 contiguous dest elems per thread.
// granules: fcWb 640000 | Wcat2 262144 | Wxg 131072 | W_hb 16384
//  Wfb 16384 | featb 401408 | linx 155648 | bias 256 | bfh 32
//  hx0 8192 | cx0 8192  => 1,639,712 granules = 6406 blocks x 256
// ------------------------------------------------------------------
__global__ __launch_bounds__(256) void k_prep(
    const float* __restrict__ fc_W, const float* __restrict__ W_ih,
    const float* __restrict__ W_hh, const float* __restrict__ W_h,
    const float* __restrict__ W_f, const float* __restrict__ features,
    const float* __restrict__ emb, const int* __restrict__ captions,
    const float* __restrict__ b_ih, const float* __restrict__ b_hh,
    const float* __restrict__ b_f, const float* __restrict__ b_h,
    bf16_t* __restrict__ fcWb, bf16_t* __restrict__ Wcat2,
    bf16_t* __restrict__ Wxg, bf16_t* __restrict__ W_hb,
    bf16_t* __restrict__ Wfb, bf16_t* __restrict__ featb,
    bf16_t* __restrict__ linx, float* __restrict__ bias,
    float* __restrict__ bfh, float* __restrict__ hx, float* __restrict__ cx)
{
    int g = blockIdx.x * 256 + threadIdx.x;
    if (g < 640000) { int idx = g * 8; cvt8(fcWb + idx, fc_W + idx); return; }
    g -= 640000;
    if (g < 262144) {   // Wcat2[2048][1024] = [Wc | Whh], row n'=4h+g
        int idx = g * 8;
        int row = idx >> 10, col = idx & 1023;
        int orig = (row & 3) * NH + (row >> 2);
        const float* src = (col < 512) ? (W_ih + (size_t)orig * 1024 + 512 + col)
                                       : (W_hh + (size_t)orig * 512 + (col - 512));
        cvt8(Wcat2 + idx, src);
        return;
    }
    g -= 262144;
    if (g < 131072) {   // Wxg[2048][512] = x-part, row n'=4h+g
        int idx = g * 8;
        int row = idx >> 9, col = idx & 511;
        int orig = (row & 3) * NH + (row >> 2);
        cvt8(Wxg + idx, W_ih + (size_t)orig * 1024 + col);
        return;
    }
    g -= 131072;
    if (g < 16384) { int idx = g * 8; cvt8(W_hb + idx, W_h + idx); return; }
    g -= 16384;
    if (g < 16384) { int idx = g * 8; cvt8(Wfb + idx, W_f + idx); return; }
    g -= 16384;
    if (g < 401408) { int idx = g * 8; cvt8(featb + idx, features + idx); return; }
    g -= 401408;
    if (g < 155648) {   // linx[2432][512]: emb gather, row = t*128+b
        int idx = g * 8;
        int row = idx >> 9, col = idx & 511;
        int t = row >> 7, b = row & 127;
        int cap = captions[b * NT + t];
        cvt8(linx + idx, emb + (size_t)cap * NE + col);
        return;
    }
    g -= 155648;
    if (g < 256) {      // bias reorder (f32)
        int n0 = g * 8;
        #pragma unroll
        for (int i = 0; i < 8; ++i) {
            int n = n0 + i, h = n >> 2, gg = n & 3;
            int orig = gg * NH + h;
            bias[n] = b_ih[orig] + b_hh[orig];
        }
        return;
    }
    g -= 256;
    if (g < 32) {       // bfh = b_f + b_h (folded into fproj)
        int n0 = g * 8;
        #pragma unroll
        for (int i = 0; i < 8; ++i) bfh[n0 + i] = b_f[n0 + i] + b_h[n0 + i];
        return;
    }
    g -= 32;
    float4 z = make_float4(0.f, 0.f, 0.f, 0.f);
    if (g < 8192) { *(float4*)(hx + g * 8) = z; *(float4*)(hx + g * 8 + 4) = z; return; }
    g -= 8192;
    if (g < 8192) { *(float4*)(cx + g * 8) = z; *(float4*)(cx + g * 8 + 4) = z; }
}

// ------------------------------------------------------------------
// generic bf16 MFMA GEMM-NT: C[M,N] = A[M,K] @ B[N,K]^T (+bias)
// tile 64x64, BK=64, 4 waves. Cb!=null -> bf16 output, else f32 to Cf.
// ------------------------------------------------------------------
__global__ __launch_bounds__(256) void gemm_bf16_nt(
    const bf16_t* __restrict__ Am, const bf16_t* __restrict__ Bm,
    const float* __restrict__ bias, float* __restrict__ Cf,
    bf16_t* __restrict__ Cb, int M, int N, int K, int ldc)
{
    __shared__ uint4 AsU[512];
    __shared__ uint4 BsU[512];
    int tid = threadIdx.x;
    int m0 = blockIdx.x * 64, n0 = blockIdx.y * 64;
    int nk = K >> 6;

    int rowS = tid >> 3, slotS = tid & 7;
    int wr0 = rowS * 8 + (slotS ^ (rowS & 7));
    int rowS2 = rowS + 32;
    int wr1 = rowS2 * 8 + (slotS ^ (rowS2 & 7));

    const uint4* pA = (const uint4*)(Am + (size_t)(m0 + rowS) * K) + slotS;
    size_t aStep = (size_t)4 * K;
    int nrow0 = n0 + rowS, nrow1 = n0 + rowS2;
    bool bv0 = nrow0 < N, bv1 = nrow1 < N;
    const uint4* pB0 = (const uint4*)(Bm + (size_t)nrow0 * K) + slotS;
    const uint4* pB1 = (const uint4*)(Bm + (size_t)nrow1 * K) + slotS;
    uint4 zz = make_uint4(0, 0, 0, 0);

    int w = tid >> 6, lane = tid & 63;
    int wm = w >> 1, wn = w & 1;
    int lr = lane & 15, lg = lane >> 4;
    int ra[2][2], rb[2][2];
    #pragma unroll
    for (int i = 0; i < 2; ++i)
        #pragma unroll
        for (int kk = 0; kk < 2; ++kk) {
            int rA = wm * 32 + i * 16 + lr;
            int rB = wn * 32 + i * 16 + lr;
            int s = kk * 4 + lg;
            ra[i][kk] = rA * 8 + (s ^ (rA & 7));
            rb[i][kk] = rB * 8 + (s ^ (rB & 7));
        }

    f32x4 acc00 = {}, acc01 = {}, acc10 = {}, acc11 = {};
    uint4 a0 = pA[0], a1 = pA[aStep];
    uint4 b0 = bv0 ? pB0[0] : zz;
    uint4 b1 = bv1 ? pB1[0] : zz;
    pA += 8; pB0 += 8; pB1 += 8;

    #pragma unroll 1
    for (int kt = 0; kt < nk; ++kt) {
        __syncthreads();
        AsU[wr0] = a0; AsU[wr1] = a1;
        BsU[wr0] = b0; BsU[wr1] = b1;
        if (kt + 1 < nk) {
            a0 = pA[0]; a1 = pA[aStep];
            b0 = bv0 ? pB0[0] : zz;
            b1 = bv1 ? pB1[0] : zz;
            pA += 8; pB0 += 8; pB1 += 8;
        }
        __syncthreads();
        const bf16x8* Af = (const bf16x8*)AsU;
        const bf16x8* Bf = (const bf16x8*)BsU;
        #pragma unroll
        for (int kk = 0; kk < 2; ++kk) {
            bf16x8 fa0 = Af[ra[0][kk]], fa1 = Af[ra[1][kk]];
            bf16x8 fb0 = Bf[rb[0][kk]], fb1 = Bf[rb[1][kk]];
            acc00 = __builtin_amdgcn_mfma_f32_16x16x32_bf16(fa0, fb0, acc00, 0, 0, 0);
            acc01 = __builtin_amdgcn_mfma_f32_16x16x32_bf16(fa0, fb1, acc01, 0, 0, 0);
            acc10 = __builtin_amdgcn_mfma_f32_16x16x32_bf16(fa1, fb0, acc10, 0, 0, 0);
            acc11 = __builtin_amdgcn_mfma_f32_16x16x32_bf16(fa1, fb1, acc11, 0, 0, 0);
        }
    }

    f32x4 av[2][2] = {{acc00, acc01}, {acc10, acc11}};
    #pragma unroll
    for (int i = 0; i < 2; ++i) {
        int mbase = m0 + wm * 32 + i * 16 + lg * 4;
        #pragma unroll
        for (int j = 0; j < 2; ++j) {
            int n = n0 + wn * 32 + j * 16 + lr;
            if (n < N) {
                float bz = bias ? bias[n] : 0.f;
                #pragma unroll
                for (int r = 0; r < 4; ++r) {
                    float v = av[i][j][r] + bz;
                    if (Cb) Cb[(size_t)(mbase + r) * ldc + n] = (bf16_t)v;
                    else    Cf[(size_t)(mbase + r) * ldc + n] = v;
                }
            }
        }
    }
}

// ------------------------------------------------------------------
// attention: block b, 512 threads. fproj is bf16 with b_f+b_h folded.
// Writes lin row = [ctx | hx] (bf16).
// ------------------------------------------------------------------
__global__ __launch_bounds__(512) void k_attn(
    const float* __restrict__ hx, const bf16_t* __restrict__ W_hb,
    const bf16_t* __restrict__ fprojb, const float* __restrict__ v_w,
    const bf16_t* __restrict__ featb, bf16_t* __restrict__ lin)
{
    int b = blockIdx.x;
    int tid = threadIdx.x;
    int w = tid >> 6, lane = tid & 63;
    __shared__ float hxs[NH];
    __shared__ float part[2][NA];
    __shared__ float salpha[64];

    hxs[tid] = hx[b * NH + tid];
    __syncthreads();

    {   // h = hx @ W_h^T : thread (q = tid>>8, a = tid&255), half-K dot
        int a = tid & 255, q = tid >> 8;
        const bf16x8* wrow = (const bf16x8*)(W_hb + (size_t)a * NH + q * 256);
        const float* hq = hxs + q * 256;
        float p = 0.f;
        #pragma unroll
        for (int c = 0; c < 32; ++c) {
            bf16x8 wv = wrow[c];
            int k = c * 8;
            p += hq[k+0]*(float)wv[0] + hq[k+1]*(float)wv[1]
               + hq[k+2]*(float)wv[2] + hq[k+3]*(float)wv[3]
               + hq[k+4]*(float)wv[4] + hq[k+5]*(float)wv[5]
               + hq[k+6]*(float)wv[6] + hq[k+7]*(float)wv[7];
        }
        part[q][a] = p;
    }
    __syncthreads();

    {   // scores: 8 waves strided over r
        for (int r = w; r < NR; r += 8) {
            const bf16_t* fp = fprojb + ((size_t)b * NR + r) * NA;
            float s = 0.f;
            #pragma unroll
            for (int j = 0; j < 4; ++j) {
                int aa = lane + 64 * j;
                float hv = part[0][aa] + part[1][aa];
                s += tanhf(hv + (float)fp[aa]) * v_w[aa];
            }
            #pragma unroll
            for (int off = 32; off; off >>= 1) s += __shfl_xor(s, off);
            if (lane == 0) salpha[r] = s;
        }
    }
    __syncthreads();

    if (tid < 64) {   // softmax over R=49 in wave 0
        float v = (tid < NR) ? salpha[tid] : -INFINITY;
        float m = v;
        #pragma unroll
        for (int off = 32; off; off >>= 1) m = fmaxf(m, __shfl_xor(m, off));
        float e = (tid < NR) ? expf(v - m) : 0.f;
        float ssum = e;
        #pragma unroll
        for (int off = 32; off; off >>= 1) ssum += __shfl_xor(ssum, off);
        if (tid < NR) salpha[tid] = e / ssum;
    }
    __syncthreads();

    {   // context + [ctx | hx] row
        bf16_t* lrow = lin + (size_t)b * NK2;
        float c = 0.f;
        #pragma unroll 7
        for (int r = 0; r < NR; ++r)
            c += salpha[r] * (float)featb[((size_t)b * NR + r) * NFD + tid];
        lrow[tid] = (bf16_t)c;
        lrow[NFD + tid] = (bf16_t)hxs[tid];
    }
}

// ------------------------------------------------------------------
// fused step: gates GEMM (128 x 2048 x 1024) + LSTM epilogue.
// grid (4,32): tile 32 batches x 64 gate-cols. 4 waves: wm=w&1 (m-half),
// wn=w>>1 (n-half); per wave 16x32 = 1 m-frag x 2 n-frags.
// gates = lin@Wcat2^T + pre_x[t] + bias.
// ------------------------------------------------------------------
__global__ __launch_bounds__(256) void k_step(
    const bf16_t* __restrict__ lin, const bf16_t* __restrict__ Wcat2,
    const bf16_t* __restrict__ pre_x, const float* __restrict__ bias,
    float* __restrict__ hx, float* __restrict__ cx,
    bf16_t* __restrict__ hxAll, int t)
{
    __shared__ __align__(16) char smem[12288];
    uint4* AsU = (uint4*)smem;          // [256]  32 rows x 8 slots
    uint4* BsU = AsU + 256;             // [512]  64 rows x 8 slots

    int tid = threadIdx.x;
    int m0 = blockIdx.x * 32, n0 = blockIdx.y * 64;

    int rowS = tid >> 3, slotS = tid & 7;     // rowS 0..31
    int wrA = rowS * 8 + (slotS ^ (rowS & 7));
    int rowB2 = rowS + 32;
    int wrB1 = rowB2 * 8 + (slotS ^ (rowB2 & 7));

    const uint4* pA  = (const uint4*)(lin   + (size_t)(m0 + rowS) * NK2) + slotS;
    const uint4* pB0 = (const uint4*)(Wcat2 + (size_t)(n0 + rowS) * NK2) + slotS;
    const uint4* pB1 = (const uint4*)(Wcat2 + (size_t)(n0 + rowB2) * NK2) + slotS;

    int w = tid >> 6, lane = tid & 63;
    int wm = w & 1, wn = w >> 1;
    int lr = lane & 15, lg = lane >> 4;
    int raI[2], rbI[2][2];
    #pragma unroll
    for (int kk = 0; kk < 2; ++kk) {
        int rA = wm * 16 + lr;
        int s = kk * 4 + lg;
        raI[kk] = rA * 8 + (s ^ (rA & 7));
        #pragma unroll
        for (int j = 0; j < 2; ++j) {
            int rB = wn * 32 + j * 16 + lr;
            rbI[j][kk] = rB * 8 + (s ^ (rB & 7));
        }
    }

    f32x4 acc0 = {}, acc1 = {};
    uint4 a0 = pA[0], b0 = pB0[0], b1 = pB1[0];
    pA += 8; pB0 += 8; pB1 += 8;

    #pragma unroll 1
    for (int kt = 0; kt < NK2 / 64; ++kt) {
        __syncthreads();
        AsU[wrA] = a0; BsU[wrA] = b0; BsU[wrB1] = b1;
        if (kt + 1 < NK2 / 64) {
            a0 = pA[0]; b0 = pB0[0]; b1 = pB1[0];
            pA += 8; pB0 += 8; pB1 += 8;
        }
        __syncthreads();
        const bf16x8* Af = (const bf16x8*)AsU;
        const bf16x8* Bf = (const bf16x8*)BsU;
        #pragma unroll
        for (int kk = 0; kk < 2; ++kk) {
            bf16x8 fa  = Af[raI[kk]];
            bf16x8 fb0 = Bf[rbI[0][kk]];
            bf16x8 fb1 = Bf[rbI[1][kk]];
            acc0 = __builtin_amdgcn_mfma_f32_16x16x32_bf16(fa, fb0, acc0, 0, 0, 0);
            acc1 = __builtin_amdgcn_mfma_f32_16x16x32_bf16(fa, fb1, acc1, 0, 0, 0);
        }
    }

    __syncthreads();
    float* Ct = (float*)smem;   // [32][65]
    {
        int crow = wm * 16 + lg * 4;
        #pragma unroll
        for (int r = 0; r < 4; ++r) {
            Ct[(crow + r) * 65 + wn * 32 + lr]      = acc0[r];
            Ct[(crow + r) * 65 + wn * 32 + 16 + lr] = acc1[r];
        }
    }
    __syncthreads();

    int hloc = tid & 15;
    int h = (n0 >> 2) + hloc;
    #pragma unroll
    for (int q = 0; q < 2; ++q) {
        int m = (tid >> 4) + q * 16;
        int bb = m0 + m;
        const float* crow = Ct + m * 65 + hloc * 4;
        const float* brow = bias + n0 + hloc * 4;
        const bf16_t* prow = pre_x + ((size_t)t * NB + bb) * NG + n0 + hloc * 4;
        float gi = crow[0] + brow[0] + (float)prow[0];
        float gf = crow[1] + brow[1] + (float)prow[1];
        float gg = crow[2] + brow[2] + (float)prow[2];
        float go = crow[3] + brow[3] + (float)prow[3];
        size_t idx = (size_t)bb * NH + h;
        float c = sigm(gf) * cx[idx] + sigm(gi) * tanhf(gg);
        float hn = sigm(go) * tanhf(c);
        cx[idx] = c;
        hx[idx] = hn;
        hxAll[((size_t)t * NB + bb) * NH + h] = (bf16_t)hn;
    }
}

// ------------------------------------------------------------------
// batched logits GEMM — reverted to the empirically-fast R3 structure:
// 64x64 tile, 2D grid (38,157), per-lane scatter epilogue, PLUS
// nontemporal stores so the 97MB fp32 output doesn't churn L2/L3.
// A = hxAll [2432, 512] bf16, B = fcWb [10000, 512].
// C row m (m = t*128+b) -> out[(b*19+t)*10000 + n].
// ------------------------------------------------------------------
__global__ __launch_bounds__(256) void k_logits(
    const bf16_t* __restrict__ hxAll, const bf16_t* __restrict__ fcWb,
    const float* __restrict__ fc_b, float* __restrict__ out)
{
    __shared__ uint4 AsU[512];
    __shared__ uint4 BsU[512];
    int tid = threadIdx.x;
    int m0 = blockIdx.x * 64, n0 = blockIdx.y * 64;

    int rowS = tid >> 3, slotS = tid & 7;
    int wr0 = rowS * 8 + (slotS ^ (rowS & 7));
    int rowS2 = rowS + 32;
    int wr1 = rowS2 * 8 + (slotS ^ (rowS2 & 7));

    const uint4* pA = (const uint4*)(hxAll + (size_t)(m0 + rowS) * NH) + slotS;
    size_t aStep = (size_t)4 * NH;
    int nrow0 = n0 + rowS, nrow1 = n0 + rowS2;
    bool bv0 = nrow0 < NV, bv1 = nrow1 < NV;
    const uint4* pB0 = (const uint4*)(fcWb + (size_t)nrow0 * NH) + slotS;
    const uint4* pB1 = (const uint4*)(fcWb + (size_t)nrow1 * NH) + slotS;
    uint4 zz = make_uint4(0, 0, 0, 0);

    int w = tid >> 6, lane = tid & 63;
    int wm = w >> 1, wn = w & 1;
    int lr = lane & 15, lg = lane >> 4;
    int ra[2][2], rb[2][2];
    #pragma unroll
    for (int i = 0; i < 2; ++i)
        #pragma unroll
        for (int kk = 0; kk < 2; ++kk) {
            int rA = wm * 32 + i * 16 + lr;
            int rB = wn * 32 + i * 16 + lr;
            int s = kk * 4 + lg;
            ra[i][kk] = rA * 8 + (s ^ (rA & 7));
            rb[i][kk] = rB * 8 + (s ^ (rB & 7));
        }

    f32x4 acc00 = {}, acc01 = {}, acc10 = {}, acc11 = {};
    uint4 a0 = pA[0], a1 = pA[aStep];
    uint4 b0 = bv0 ? pB0[0] : zz;
    uint4 b1 = bv1 ? pB1[0] : zz;
    pA += 8; pB0 += 8; pB1 += 8;

    #pragma unroll 1
    for (int kt = 0; kt < NH / 64; ++kt) {
        __syncthreads();
        AsU[wr0] = a0; AsU[wr1] = a1;
        BsU[wr0] = b0; BsU[wr1] = b1;
        if (kt + 1 < NH / 64) {
            a0 = pA[0]; a1 = pA[aStep];
            b0 = bv0 ? pB0[0] : zz;
            b1 = bv1 ? pB1[0] : zz;
            pA += 8; pB0 += 8; pB1 += 8;
        }
        __syncthreads();
        const bf16x8* Af = (const bf16x8*)AsU;
        const bf16x8* Bf = (const bf16x8*)BsU;
        #pragma unroll
        for (int kk = 0; kk < 2; ++kk) {
            bf16x8 fa0 = Af[ra[0][kk]], fa1 = Af[ra[1][kk]];
            bf16x8 fb0 = Bf[rb[0][kk]], fb1 = Bf[rb[1][kk]];
            acc00 = __builtin_amdgcn_mfma_f32_16x16x32_bf16(fa0, fb0, acc00, 0, 0, 0);
            acc01 = __builtin_amdgcn_mfma_f32_16x16x32_bf16(fa0, fb1, acc01, 0, 0, 0);
            acc10 = __builtin_amdgcn_mfma_f32_16x16x32_bf16(fa1, fb0, acc10, 0, 0, 0);
            acc11 = __builtin_amdgcn_mfma_f32_16x16x32_bf16(fa1, fb1, acc11, 0, 0, 0);
        }
    }

    f32x4 av[2][2] = {{acc00, acc01}, {acc10, acc11}};
    #pragma unroll
    for (int i = 0; i < 2; ++i) {
        int mbase = m0 + wm * 32 + i * 16 + lg * 4;
        #pragma unroll
        for (int j = 0; j < 2; ++j) {
            int n = n0 + wn * 32 + j * 16 + lr;
            if (n < NV) {
                float bz = fc_b[n];
                #pragma unroll
                for (int r = 0; r < 4; ++r) {
                    int m = mbase + r;
                    int bb = m & 127, tt = m >> 7;
                    __builtin_nontemporal_store(
                        av[i][j][r] + bz,
                        out + ((size_t)bb * NS + tt) * NV + n);
                }
            }
        }
    }
}

// ------------------------------------------------------------------
extern "C" void kernel_launch(void* const* d_in, const int* in_sizes, int n_in,
                              void* d_out, int out_size, void* d_ws, size_t ws_size,
                              hipStream_t stream)
{
    const float* features = (const float*)d_in[0];
    const int*   captions = (const int*)d_in[1];
    const float* emb      = (const float*)d_in[2];
    const float* W_h      = (const float*)d_in[3];
    const float* b_h      = (const float*)d_in[4];
    const float* W_f      = (const float*)d_in[5];
    const float* b_f      = (const float*)d_in[6];
    const float* v_w      = (const float*)d_in[7];
    // d_in[8] = v_b : cancels in softmax
    const float* W_ih     = (const float*)d_in[9];
    const float* W_hh     = (const float*)d_in[10];
    const float* b_ih     = (const float*)d_in[11];
    const float* b_hh     = (const float*)d_in[12];
    const float* fc_W     = (const float*)d_in[13];
    const float* fc_b     = (const float*)d_in[14];
    float* out = (float*)d_out;

    char* base = (char*)d_ws;
    bf16_t* fcWb   = (bf16_t*)base;  base += (size_t)NV * NH * 2;
    bf16_t* Wcat2  = (bf16_t*)base;  base += (size_t)NG * NK2 * 2;
    bf16_t* Wxg    = (bf16_t*)base;  base += (size_t)NG * NE * 2;
    bf16_t* W_hb   = (bf16_t*)base;  base += (size_t)NA * NH * 2;
    bf16_t* Wfb    = (bf16_t*)base;  base += (size_t)NA * NFD * 2;
    bf16_t* featb  = (bf16_t*)base;  base += (size_t)NB * NR * NFD * 2;
    bf16_t* linx   = (bf16_t*)base;  base += (size_t)NS * NB * NE * 2;
    bf16_t* pre_x  = (bf16_t*)base;  base += (size_t)NS * NB * NG * 2;
    bf16_t* lin    = (bf16_t*)base;  base += (size_t)NB * NK2 * 2;
    bf16_t* hxAll  = (bf16_t*)base;  base += (size_t)NS * NB * NH * 2;
    bf16_t* fprojb = (bf16_t*)base;  base += (size_t)NB * NR * NA * 2;
    float*  bias   = (float*)base;   base += (size_t)NG * 4;
    float*  bfh    = (float*)base;   base += (size_t)NA * 4;
    float*  hx     = (float*)base;   base += (size_t)NB * NH * 4;
    float*  cx     = (float*)base;   base += (size_t)NB * NH * 4;
    // total ~42.5 MB

    k_prep<<<dim3(6406), 256, 0, stream>>>(
        fc_W, W_ih, W_hh, W_h, W_f, features, emb, captions, b_ih, b_hh,
        b_f, b_h, fcWb, Wcat2, Wxg, W_hb, Wfb, featb, linx, bias, bfh, hx, cx);

    // f_proj = features @ W_f^T + (b_f + b_h) : (6272 x 256), K=512, bf16 out
    gemm_bf16_nt<<<dim3(98, 4), 256, 0, stream>>>(
        featb, Wfb, bfh, (float*)0, fprojb, NB * NR, NA, NFD, NA);

    // pre_x = linx @ Wxg^T : (2432 x 2048), K=512, bf16 out, no bias
    gemm_bf16_nt<<<dim3(38, 32), 256, 0, stream>>>(
        linx, Wxg, (const float*)0, (float*)0, pre_x, NS * NB, NG, NE, NG);

    for (int t = 0; t < NS; ++t) {
        k_attn<<<dim3(NB), 512, 0, stream>>>(
            hx, W_hb, fprojb, v_w, featb, lin);
        k_step<<<dim3(4, 32), 256, 0, stream>>>(
            lin, Wcat2, pre_x, bias, hx, cx, hxAll, t);
    }

    // batched logits: (2432 x 10000), K=512, 64x64 tiles, nt-store epilogue
    k_logits<<<dim3(38, 157), 256, 0, stream>>>(hxAll, fcWb, fc_b, out);
}